// Round 11
// baseline (3061.232 us; speedup 1.0000x reference)
//
#include <hip/hip_runtime.h>
#include <hip/hip_bf16.h>
#include <stdint.h>

#define SEQ 2048
#define DIMSZ 4096
#define QKVN 6144   // 4096 Q + 1024 K + 1024 V

typedef __attribute__((ext_vector_type(8))) __bf16 bf16x8;
typedef __attribute__((ext_vector_type(4))) float f32x4;

// async global->LDS, 16B per lane; dest = wave-uniform base + lane*16
static __device__ __forceinline__ void gld_lds16(const void* g, void* l) {
  __builtin_amdgcn_global_load_lds(
      (__attribute__((address_space(1))) void*)(g),
      (__attribute__((address_space(3))) void*)(l), 16, 0, 0);
}

// ---------------- merged fp32 -> bf16 conversion (one launch, 5 segments) --
__global__ __launch_bounds__(256) void k_cvt5(const float* __restrict__ x,
                                              const float* __restrict__ wq,
                                              const float* __restrict__ wk,
                                              const float* __restrict__ wv,
                                              const float* __restrict__ wo,
                                              __bf16* __restrict__ xb,
                                              __bf16* __restrict__ wqkvb,
                                              __bf16* __restrict__ wob) {
  long vid = (long)blockIdx.x * 256 + threadIdx.x;
  const long stride = (long)gridDim.x * 256;
  for (; vid < 7340032L; vid += stride) {
    const float* src; __bf16* dst; long off;
    if (vid < 2097152L)      { src = x;  dst = xb;                off = vid; }
    else if (vid < 4194304L) { src = wq; dst = wqkvb;             off = vid - 2097152L; }
    else if (vid < 4718592L) { src = wk; dst = wqkvb + 16777216L; off = vid - 4194304L; }
    else if (vid < 5242880L) { src = wv; dst = wqkvb + 20971520L; off = vid - 4718592L; }
    else                     { src = wo; dst = wob;               off = vid - 5242880L; }
    const long e = off * 8;
    float4 v0 = *(const float4*)(src + e);
    float4 v1 = *(const float4*)(src + e + 4);
    bf16x8 o;
    o[0] = (__bf16)v0.x; o[1] = (__bf16)v0.y; o[2] = (__bf16)v0.z; o[3] = (__bf16)v0.w;
    o[4] = (__bf16)v1.x; o[5] = (__bf16)v1.y; o[6] = (__bf16)v1.z; o[7] = (__bf16)v1.w;
    *(bf16x8*)(dst + e) = o;
  }
}

// ---------------- GEMM1: C = A * B^T, 256x384 tile, BK=32, 256 blocks ------
// Balanced grid (r10 PM: GEMM1's 848 vs GEMM2's 1123 TF = exactly the 1.5/2
// round packing loss). 16x16 = 256 blocks = 1/CU, zero tail; 80 KiB LDS ->
// 2 blocks/CU for cross-block stall cover. 8 waves (2M x 4N): per-wave
// 128x96, acc[8][6]. Per K-tile (c=T&1):
//  ph0: read a[0..7]+b[0..2] (11 b128); stage B(T+1)->Bs[c^1] (3 gld);
//       bar; lgkmcnt(0); setprio1; 24 MFMA; setprio0; bar
//  ph1: read b[3..5] (3); stage A(T+2)->As[c] (2 gld; A reads ended ph0 +
//       barrier -> race-free); bar; lgkmcnt(0); setprio1; 24 MFMA; setprio0;
//       s_waitcnt vmcnt(2)  <- counted: retires A(T+1),B(T+1), keeps A(T+2);
//       bar
// Queue walk (oldest first) at end of T: [A(T+1)2, B(T+1)3, A(T+2)2] ->
// vmcnt(2) leaves A(T+2) ✓. Prologue A(0),B(0),A(1) + vmcnt(2) matches.
// T2 swizzle: 16B chunk ^= (row>>1)&3 via pre-swizzled source (0 conflicts
// measured r5-r10); read side rsw=(lr>>1)&3.
__global__ __launch_bounds__(512, 4) void k_gemm384(const __bf16* __restrict__ A,
                                                    const __bf16* __restrict__ B,
                                                    __bf16* __restrict__ C,
                                                    int M, int N, int K) {
  __shared__ __align__(16) __bf16 As[2][256 * 32];  // 32 KiB
  __shared__ __align__(16) __bf16 Bs[2][384 * 32];  // 48 KiB
  const int t = threadIdx.x;
  const int l = t & 63;
  const int w = t >> 6;        // 0..7
  const int wm = w >> 2;       // 0..1 : rows wm*128..+128
  const int wn = w & 3;        // 0..3 : cols wn*96..+96
  const int lr = l & 15, lg = l >> 4;
  const int rsw = (lr >> 1) & 3;
  const int bm = blockIdx.y, bn = blockIdx.x;

  // staging: one gld_lds issue = 512 thr x 16B = 128 rows x 32 cols.
  // thread t -> row t>>2, chunk t&3; source chunk pre-swizzled ^ (t>>3)&3.
  const int scol = (((t & 3) ^ ((t >> 3) & 3)) << 3);
  const __bf16* pA0 = A + (size_t)(bm * 256 + (t >> 2)) * K + scol;
  const __bf16* pA1 = pA0 + (size_t)128 * K;
  const __bf16* pB0 = B + (size_t)(bn * 384 + (t >> 2)) * K + scol;
  const __bf16* pB1 = pB0 + (size_t)128 * K;
  const __bf16* pB2 = pB0 + (size_t)256 * K;
  const int t8 = t * 8;

#define SA(buf, kc) { gld_lds16(pA0 + (kc), &As[buf][t8]);        \
                      gld_lds16(pA1 + (kc), &As[buf][4096 + t8]); }
#define SB(buf, kc) { gld_lds16(pB0 + (kc), &Bs[buf][t8]);        \
                      gld_lds16(pB1 + (kc), &Bs[buf][4096 + t8]); \
                      gld_lds16(pB2 + (kc), &Bs[buf][8192 + t8]); }

  const int cc = ((lg ^ rsw) * 8);   // read chunk offset (elems)
  f32x4 acc[8][6] = {};
  const int nt = K >> 5;             // 128 K-tiles

#define PHTOP()                                        \
  asm volatile("" ::: "memory");                       \
  __builtin_amdgcn_s_barrier();                        \
  asm volatile("s_waitcnt lgkmcnt(0)" ::: "memory");   \
  __builtin_amdgcn_s_setprio(1)
#define PHEND()                                        \
  __builtin_amdgcn_s_setprio(0);                       \
  asm volatile("" ::: "memory");                       \
  __builtin_amdgcn_s_barrier()
#define PHENDW()                                       \
  __builtin_amdgcn_s_setprio(0);                       \
  asm volatile("s_waitcnt vmcnt(2)" ::: "memory");     \
  __builtin_amdgcn_s_barrier()

  // prologue: A(0), B(0), A(1) = 7 loads; vmcnt(2) -> tile 0 landed
  SA(0, 0); SB(0, 0); SA(1, 32);
  asm volatile("s_waitcnt vmcnt(2)" ::: "memory");
  asm volatile("" ::: "memory");
  __builtin_amdgcn_s_barrier();
  asm volatile("" ::: "memory");

  for (int T = 0; T < nt; ++T) {
    const int c = T & 1;
    const int kB = (T + 1 < nt ? T + 1 : nt - 1) << 5;
    const int kA = (T + 2 < nt ? T + 2 : nt - 1) << 5;
    bf16x8 a[8], b[3];

    // ---- ph0: a(all) x b0..2 ----
#pragma unroll
    for (int mi = 0; mi < 8; ++mi)
      a[mi] = *(const bf16x8*)&As[c][(wm * 128 + mi * 16 + lr) * 32 + cc];
#pragma unroll
    for (int j = 0; j < 3; ++j)
      b[j] = *(const bf16x8*)&Bs[c][(wn * 96 + j * 16 + lr) * 32 + cc];
    SB(c ^ 1, kB);
    PHTOP();
#pragma unroll
    for (int mi = 0; mi < 8; ++mi)
#pragma unroll
      for (int j = 0; j < 3; ++j)
        acc[mi][j] = __builtin_amdgcn_mfma_f32_16x16x32_bf16(a[mi], b[j], acc[mi][j], 0, 0, 0);
    PHEND();

    // ---- ph1: a(all) x b3..5; stage A(T+2) into As[c] (reads done ph0) ----
#pragma unroll
    for (int j = 0; j < 3; ++j)
      b[j] = *(const bf16x8*)&Bs[c][(wn * 96 + (j + 3) * 16 + lr) * 32 + cc];
    SA(c, kA);
    PHTOP();
#pragma unroll
    for (int mi = 0; mi < 8; ++mi)
#pragma unroll
      for (int j = 0; j < 3; ++j)
        acc[mi][j + 3] = __builtin_amdgcn_mfma_f32_16x16x32_bf16(a[mi], b[j], acc[mi][j + 3], 0, 0, 0);
    PHENDW();
  }
#undef SA
#undef SB
#undef PHTOP
#undef PHEND
#undef PHENDW

  const int row0 = bm * 256 + wm * 128;
  const int col0 = bn * 384 + wn * 96;
#pragma unroll
  for (int mi = 0; mi < 8; ++mi)
#pragma unroll
    for (int ni = 0; ni < 6; ++ni)
#pragma unroll
      for (int r = 0; r < 4; ++r)
        C[(size_t)(row0 + mi * 16 + lg * 4 + r) * N + (col0 + ni * 16 + lr)] =
            (__bf16)acc[mi][ni][r];
}

// ---------------- GEMM2: round-10 8-phase 256x256 kernel (unchanged) -------
template <typename OutT>
__global__ __launch_bounds__(512) void k_gemm8p(const __bf16* __restrict__ A,
                                                const __bf16* __restrict__ B,
                                                OutT* __restrict__ C,
                                                int M, int N, int K) {
  __shared__ __align__(16) __bf16 As[2][2][128 * 64];  // 64 KiB
  __shared__ __align__(16) __bf16 Bs[2][2][128 * 64];  // 64 KiB
  const int t = threadIdx.x;
  const int l = t & 63;
  const int w = t >> 6;
  const int wm = w >> 2;
  const int wn = w & 3;
  const int lr = l & 15, lg = l >> 4;
  const int sw = lr & 7;
  const int bm = blockIdx.y, bn = blockIdx.x;

  const int srow = t >> 3;
  const int scol = ((t & 7) ^ (srow & 7)) << 3;
  const __bf16* pa0 = A + (size_t)(bm * 256 +   0 + srow) * K + scol;
  const __bf16* pa1 = A + (size_t)(bm * 256 +  64 + srow) * K + scol;
  const __bf16* pa2 = A + (size_t)(bm * 256 + 128 + srow) * K + scol;
  const __bf16* pa3 = A + (size_t)(bm * 256 + 192 + srow) * K + scol;
  const __bf16* pb0 = B + (size_t)(bn * 256 +   0 + srow) * K + scol;
  const __bf16* pb1 = B + (size_t)(bn * 256 +  64 + srow) * K + scol;
  const __bf16* pb2 = B + (size_t)(bn * 256 + 128 + srow) * K + scol;
  const __bf16* pb3 = B + (size_t)(bn * 256 + 192 + srow) * K + scol;
  const int ldst = t * 8;

#define SA0(buf, kc) { gld_lds16(pa0 + (kc), &As[buf][0][ldst]); gld_lds16(pa1 + (kc), &As[buf][0][4096 + ldst]); }
#define SA1(buf, kc) { gld_lds16(pa2 + (kc), &As[buf][1][ldst]); gld_lds16(pa3 + (kc), &As[buf][1][4096 + ldst]); }
#define SB0(buf, kc) { gld_lds16(pb0 + (kc), &Bs[buf][0][ldst]); gld_lds16(pb1 + (kc), &Bs[buf][0][4096 + ldst]); }
#define SB1(buf, kc) { gld_lds16(pb2 + (kc), &Bs[buf][1][ldst]); gld_lds16(pb3 + (kc), &Bs[buf][1][4096 + ldst]); }

  const int c0 = ((lg ^ sw) * 8);
  const int c1 = (((lg ^ sw) ^ 4) * 8);
  const int aRow = lr;
  const int bRow = (wn & 1) * 64 + lr;

#define RDA(mi0, cur)                                                          \
  _Pragma("unroll") for (int mi = 0; mi < 4; ++mi) {                           \
    a[mi][0] = *(const bf16x8*)&As[cur][wm][(((mi0) + mi) * 16 + aRow) * 64 + c0]; \
    a[mi][1] = *(const bf16x8*)&As[cur][wm][(((mi0) + mi) * 16 + aRow) * 64 + c1]; \
  }
#define RDB(bv, ni0, cur)                                                      \
  _Pragma("unroll") for (int ni = 0; ni < 2; ++ni) {                           \
    bv[ni][0] = *(const bf16x8*)&Bs[cur][wn >> 1][(((ni0) + ni) * 16 + bRow) * 64 + c0]; \
    bv[ni][1] = *(const bf16x8*)&Bs[cur][wn >> 1][(((ni0) + ni) * 16 + bRow) * 64 + c1]; \
  }
#define PHTOP()                                        \
  asm volatile("" ::: "memory");                       \
  __builtin_amdgcn_s_barrier();                        \
  asm volatile("s_waitcnt lgkmcnt(0)" ::: "memory");   \
  __builtin_amdgcn_s_setprio(1)
#define PHEND()                                        \
  __builtin_amdgcn_s_setprio(0);                       \
  asm volatile("" ::: "memory");                       \
  __builtin_amdgcn_s_barrier()
#define PHENDW()                                       \
  __builtin_amdgcn_s_setprio(0);                       \
  asm volatile("s_waitcnt vmcnt(4)" ::: "memory");     \
  __builtin_amdgcn_s_barrier()
#define MMA16(am0, bv, ni0)                                                    \
  _Pragma("unroll") for (int mi = 0; mi < 4; ++mi)                             \
  _Pragma("unroll") for (int ni = 0; ni < 2; ++ni)                             \
  _Pragma("unroll") for (int kk = 0; kk < 2; ++kk)                             \
    acc[(am0) + mi][(ni0) + ni] = __builtin_amdgcn_mfma_f32_16x16x32_bf16(     \
        a[mi][kk], bv[ni][kk], acc[(am0) + mi][(ni0) + ni], 0, 0, 0);

  f32x4 acc[8][4] = {};
  const int nt = K >> 6;
  const int niter = nt >> 1;

  SB0(0, 0); SA0(0, 0); SA1(0, 0); SB1(0, 0);
  SB0(1, 64); SA0(1, 64);
  asm volatile("s_waitcnt vmcnt(4)" ::: "memory");
  asm volatile("" ::: "memory");
  __builtin_amdgcn_s_barrier();
  asm volatile("" ::: "memory");

  for (int i = 0; i < niter; ++i) {
    const int kT1 = (2 * i + 1) << 6;
    const int k2  = (2 * i + 2 < nt ? 2 * i + 2 : nt - 1) << 6;
    const int k3  = (2 * i + 3 < nt ? 2 * i + 3 : nt - 1) << 6;
    bf16x8 a[4][2], b0[2][2], b1[2][2];

    RDA(0, 0); RDB(b0, 0, 0);
    SA1(1, kT1);
    PHTOP(); MMA16(0, b0, 0); PHEND();
    RDB(b1, 2, 0);
    SB1(1, kT1);
    PHTOP(); MMA16(0, b1, 2); PHEND();
    RDA(4, 0);
    SB0(0, k2);
    PHTOP(); MMA16(4, b1, 2); PHEND();
    SA0(0, k2);
    PHTOP(); MMA16(4, b0, 0); PHENDW();

    RDA(0, 1); RDB(b0, 0, 1);
    SA1(0, k2);
    PHTOP(); MMA16(0, b0, 0); PHEND();
    RDB(b1, 2, 1);
    SB1(0, k2);
    PHTOP(); MMA16(0, b1, 2); PHEND();
    RDA(4, 1);
    SB0(1, k3);
    PHTOP(); MMA16(4, b1, 2); PHEND();
    SA0(1, k3);
    PHTOP(); MMA16(4, b0, 0); PHENDW();
  }
#undef SA0
#undef SA1
#undef SB0
#undef SB1
#undef RDA
#undef RDB
#undef PHTOP
#undef PHEND
#undef PHENDW
#undef MMA16

  const int row0 = bm * 256 + wm * 128;
  const int col0 = bn * 256 + wn * 64;
#pragma unroll
  for (int mi = 0; mi < 8; ++mi)
#pragma unroll
    for (int ni = 0; ni < 4; ++ni)
#pragma unroll
      for (int r = 0; r < 4; ++r)
        C[(size_t)(row0 + mi * 16 + lg * 4 + r) * N + (col0 + ni * 16 + lr)] =
            (OutT)acc[mi][ni][r];
}

// ---------------- fused RoPE + RMSNorm (in-place on Q and K regions) -------
__global__ __launch_bounds__(256) void k_rope_norm(__bf16* __restrict__ qkv,
                                                   const float* __restrict__ cosT,
                                                   const float* __restrict__ sinT) {
  const int task = blockIdx.x * 4 + (threadIdx.x >> 6);
  const int l = threadIdx.x & 63;
  const int m = task / 40;          // row in [0, 4096)
  const int h = task - m * 40;      // 0..31 = Q heads, 32..39 = K heads
  const int s = m & (SEQ - 1);
  const bool isQ = h < 32;
  const int col = isQ ? h * 128 : 4096 + (h - 32) * 128;
  __bf16* p = qkv + (size_t)m * QKVN + col + l * 2;
  float e = (float)p[0], o = (float)p[1];
  float c = cosT[s * 64 + l], sn = sinT[s * 64 + l];
  float e2 = e * c - o * sn;
  float o2 = e * sn + o * c;
  float ss = e2 * e2 + o2 * o2;
#pragma unroll
  for (int off = 32; off > 0; off >>= 1) ss += __shfl_xor(ss, off);
  float r = rsqrtf(ss * (1.0f / 128.0f) + 1e-5f);
  if (isQ) r *= 0.08838834764831845f;  // fold 1/sqrt(HEAD_DIM) into Q
  p[0] = (__bf16)(e2 * r);
  p[1] = (__bf16)(o2 * r);
}

// ---------------- V transpose: qkv V region (b,s,g,d) -> vt (b,g,d,s) ------
__global__ __launch_bounds__(256) void k_transpose_v(const __bf16* __restrict__ qkv,
                                                     __bf16* __restrict__ vt) {
  __shared__ __bf16 tile[64][136];  // padded row, no bank conflicts
  const int t = threadIdx.x;
  const int st = blockIdx.x, bg = blockIdx.y;
  const int b = bg >> 3, g = bg & 7;
  const int s0 = st * 64;
#pragma unroll
  for (int p = 0; p < 4; ++p) {
    int row = p * 16 + (t >> 4);
    int co = (t & 15) * 8;
    *(bf16x8*)&tile[row][co] =
        *(const bf16x8*)&qkv[(size_t)(b * SEQ + s0 + row) * QKVN + 5120 + g * 128 + co];
  }
  __syncthreads();
#pragma unroll
  for (int p = 0; p < 4; ++p) {
    int d = p * 32 + (t >> 3);
    int so = (t & 7) * 8;
    bf16x8 v;
#pragma unroll
    for (int j = 0; j < 8; ++j) v[j] = tile[so + j][d];
    *(bf16x8*)&vt[((size_t)bg * 128 + d) * SEQ + s0 + so] = v;
  }
}

// ---------------- causal flash attention (GQA) — round-9 version -----------
__global__ __launch_bounds__(256) void k_flash(const __bf16* __restrict__ qkv,
                                               const __bf16* __restrict__ vt,
                                               __bf16* __restrict__ attno) {
  __shared__ __bf16 Ks[64 * 128];   // [kv][d], swizzled
  __shared__ __bf16 Vs[128 * 64];   // [d][kv], swizzled
  __shared__ __bf16 Ps[4][16 * 64]; // per-wave [q][kv], swizzled
  const int t = threadIdx.x, w = t >> 6, l = t & 63;
  const int lr = l & 15, lg = l >> 4;
  const int bh = blockIdx.y;        // b*32 + h
  const int b = bh >> 5, h = bh & 31, g = h >> 2;
  const int qt0 = blockIdx.x, qt1 = 31 - (int)blockIdx.x;

  const __bf16* kp = qkv + 4096 + (size_t)(b * SEQ + (t >> 4)) * QKVN + g * 128 +
                     (((t & 15) ^ ((t >> 4) & 7)) * 8);
  const __bf16* vp = vt + (size_t)(b * 8 + g) * 128 * SEQ + (size_t)(t >> 3) * SEQ +
                     (((t & 7) ^ ((t >> 3) & 7)) * 8);
  const int wbase = (t & ~63) * 8;
  const int sw = lr & 7;

  for (int pass = 0; pass < 2; ++pass) {
    const int qt = (pass == 0) ? qt0 : qt1;

    const __bf16* Qb = qkv + (size_t)(b * SEQ + qt * 64 + w * 16 + lr) * QKVN + h * 128;
    bf16x8 qf[4];
#pragma unroll
    for (int kk = 0; kk < 4; ++kk) qf[kk] = *(const bf16x8*)&Qb[kk * 32 + lg * 8];

    f32x4 oacc[8] = {};
    float mrow[4], lsum[4];
#pragma unroll
    for (int r = 0; r < 4; ++r) { mrow[r] = -1e30f; lsum[r] = 0.f; }

    for (int kt = 0; kt <= qt; ++kt) {
      const size_t kv0 = (size_t)kt * 64;
#pragma unroll
      for (int i = 0; i < 4; ++i)
        gld_lds16(kp + (kv0 + i * 16) * QKVN, &Ks[i * 2048 + wbase]);
#pragma unroll
      for (int i = 0; i < 4; ++i)
        gld_lds16(vp + (size_t)i * 32 * SEQ + kv0, &Vs[i * 2048 + wbase]);
      __syncthreads();

      // S = Q K^T
      f32x4 sc[4] = {};
      __builtin_amdgcn_s_setprio(1);
#pragma unroll
      for (int kk = 0; kk < 4; ++kk)
#pragma unroll
        for (int n = 0; n < 4; ++n) {
          bf16x8 kf = *(const bf16x8*)&Ks[(n * 16 + lr) * 128 + ((kk * 4 + lg) ^ sw) * 8];
          sc[n] = __builtin_amdgcn_mfma_f32_16x16x32_bf16(qf[kk], kf, sc[n], 0, 0, 0);
        }
      __builtin_amdgcn_s_setprio(0);

      if (kt == qt) {  // diagonal tile: causal mask
#pragma unroll
        for (int n = 0; n < 4; ++n)
#pragma unroll
          for (int r = 0; r < 4; ++r)
            if (n * 16 + lr > w * 16 + lg * 4 + r) sc[n][r] = -1e30f;
      }

      // online softmax with defer-max (T13, THR=8)
      float pml[4];
      float need = -1e30f;
#pragma unroll
      for (int r = 0; r < 4; ++r) {
        pml[r] = fmaxf(fmaxf(sc[0][r], sc[1][r]), fmaxf(sc[2][r], sc[3][r]));
        need = fmaxf(need, pml[r] - mrow[r]);
      }
      if (__all(need <= 8.0f)) {
#pragma unroll
        for (int r = 0; r < 4; ++r) {
          float ps = 0.f;
#pragma unroll
          for (int n = 0; n < 4; ++n) { sc[n][r] = __expf(sc[n][r] - mrow[r]); ps += sc[n][r]; }
#pragma unroll
          for (int off = 8; off > 0; off >>= 1) ps += __shfl_xor(ps, off);
          lsum[r] += ps;
        }
      } else {
#pragma unroll
        for (int r = 0; r < 4; ++r) {
          float pm = pml[r];
#pragma unroll
          for (int off = 8; off > 0; off >>= 1) pm = fmaxf(pm, __shfl_xor(pm, off));
          float mn = fmaxf(mrow[r], pm);
          float corr = __expf(mrow[r] - mn);
          mrow[r] = mn;
          float ps = 0.f;
#pragma unroll
          for (int n = 0; n < 4; ++n) { sc[n][r] = __expf(sc[n][r] - mn); ps += sc[n][r]; }
#pragma unroll
          for (int off = 8; off > 0; off >>= 1) ps += __shfl_xor(ps, off);
          lsum[r] = lsum[r] * corr + ps;
#pragma unroll
          for (int dn = 0; dn < 8; ++dn) oacc[dn][r] *= corr;
        }
      }

      // P -> LDS (swizzled)
#pragma unroll
      for (int n = 0; n < 4; ++n)
#pragma unroll
        for (int r = 0; r < 4; ++r) {
          int row = lg * 4 + r;
          Ps[w][row * 64 + (((n * 2 + (lr >> 3)) ^ (row & 7)) * 8) + (lr & 7)] = (__bf16)sc[n][r];
        }

      // O += P V
      __builtin_amdgcn_s_setprio(1);
#pragma unroll
      for (int ks = 0; ks < 2; ++ks) {
        bf16x8 pf = *(const bf16x8*)&Ps[w][lr * 64 + ((ks * 4 + lg) ^ sw) * 8];
#pragma unroll
        for (int dn = 0; dn < 8; ++dn) {
          bf16x8 vf = *(const bf16x8*)&Vs[(dn * 16 + lr) * 64 + ((ks * 4 + lg) ^ sw) * 8];
          oacc[dn] = __builtin_amdgcn_mfma_f32_16x16x32_bf16(pf, vf, oacc[dn], 0, 0, 0);
        }
      }
      __builtin_amdgcn_s_setprio(0);
      __syncthreads();
    }

    float inv[4];
#pragma unroll
    for (int r = 0; r < 4; ++r) inv[r] = __builtin_amdgcn_rcpf(lsum[r]);
    __bf16* Ob = attno + (size_t)(b * SEQ + qt * 64 + w * 16) * DIMSZ + h * 128;
#pragma unroll
    for (int dn = 0; dn < 8; ++dn)
#pragma unroll
      for (int r = 0; r < 4; ++r)
        Ob[(size_t)(lg * 4 + r) * DIMSZ + dn * 16 + lr] = (__bf16)(oacc[dn][r] * inv[r]);
  }
}

// ---------------- host launcher --------------------------------------------
extern "C" void kernel_launch(void* const* d_in, const int* in_sizes, int n_in,
                              void* d_out, int out_size, void* d_ws, size_t ws_size,
                              hipStream_t stream) {
  const float* x    = (const float*)d_in[0];
  const float* wq   = (const float*)d_in[1];
  const float* wk   = (const float*)d_in[2];
  const float* wv   = (const float*)d_in[3];
  const float* wo   = (const float*)d_in[4];
  const float* cosT = (const float*)d_in[5];
  const float* sinT = (const float*)d_in[6];
  // d_in[7] (mask) implemented as causal; d_in[8] (start_pos) == 0.

  char* ws = (char*)d_ws;
  __bf16* xb    = (__bf16*)(ws);                    // 4096x4096        (32 MiB)
  __bf16* wqkvb = (__bf16*)(ws + 33554432);         // 6144x4096        (48 MiB)
  __bf16* qkvb  = (__bf16*)(ws + 83886080);         // 4096x6144        (48 MiB)
  __bf16* wob   = (__bf16*)(ws + 134217728);        // 4096x4096        (32 MiB)
  __bf16* vt    = (__bf16*)(ws + 167772160);        // 16x128x2048      ( 8 MiB)
  __bf16* attno = (__bf16*)(ws + 176160768);        // 4096x4096        (32 MiB)
  float* out = (float*)d_out;

  // fp32 -> bf16 conversions, single merged launch
  k_cvt5<<<4096, 256, 0, stream>>>(x, wq, wk, wv, wo, xb, wqkvb, wob);

  // QKV projection: M=4096, N=6144 -> 256x384 tiles, grid (16,16) = 256
  // blocks = exactly 1 round (2 blocks/CU co-schedulable at 80 KiB LDS)
  k_gemm384<<<dim3(16, 16), 512, 0, stream>>>(xb, wqkvb, qkvb, 4096, QKVN, 4096);
  // RoPE + RMSNorm on Q,K (in place), attention scale folded into Q
  k_rope_norm<<<40960, 256, 0, stream>>>(qkvb, cosT, sinT);
  // V -> V^T for contiguous PV operand reads
  k_transpose_v<<<dim3(32, 16), 256, 0, stream>>>(qkvb, vt);
  // causal GQA flash attention (paired q-tiles for balance)
  k_flash<<<dim3(16, 64), 256, 0, stream>>>(qkvb, vt, attno);
  // output projection: M=4096, N=4096 -> grid (16, 16)
  k_gemm8p<float><<<dim3(16, 16), 512, 0, stream>>>(attno, wob, out, 4096, DIMSZ, 4096);
}

// Round 12
// 697.884 us; speedup vs baseline: 4.3864x; 4.3864x over previous
//
#include <hip/hip_runtime.h>
#include <hip/hip_bf16.h>
#include <stdint.h>

#define SEQ 2048
#define DIMSZ 4096
#define QKVN 6144   // 4096 Q + 1024 K + 1024 V

typedef __attribute__((ext_vector_type(8))) __bf16 bf16x8;
typedef __attribute__((ext_vector_type(4))) float f32x4;

// async global->LDS, 16B per lane; dest = wave-uniform base + lane*16
static __device__ __forceinline__ void gld_lds16(const void* g, void* l) {
  __builtin_amdgcn_global_load_lds(
      (__attribute__((address_space(1))) void*)(g),
      (__attribute__((address_space(3))) void*)(l), 16, 0, 0);
}

// ---------------- merged fp32 -> bf16 conversion (one launch, 5 segments) --
__global__ __launch_bounds__(256) void k_cvt5(const float* __restrict__ x,
                                              const float* __restrict__ wq,
                                              const float* __restrict__ wk,
                                              const float* __restrict__ wv,
                                              const float* __restrict__ wo,
                                              __bf16* __restrict__ xb,
                                              __bf16* __restrict__ wqkvb,
                                              __bf16* __restrict__ wob) {
  long vid = (long)blockIdx.x * 256 + threadIdx.x;
  const long stride = (long)gridDim.x * 256;
  for (; vid < 7340032L; vid += stride) {
    const float* src; __bf16* dst; long off;
    if (vid < 2097152L)      { src = x;  dst = xb;                off = vid; }
    else if (vid < 4194304L) { src = wq; dst = wqkvb;             off = vid - 2097152L; }
    else if (vid < 4718592L) { src = wk; dst = wqkvb + 16777216L; off = vid - 4194304L; }
    else if (vid < 5242880L) { src = wv; dst = wqkvb + 20971520L; off = vid - 4718592L; }
    else                     { src = wo; dst = wob;               off = vid - 5242880L; }
    const long e = off * 8;
    float4 v0 = *(const float4*)(src + e);
    float4 v1 = *(const float4*)(src + e + 4);
    bf16x8 o;
    o[0] = (__bf16)v0.x; o[1] = (__bf16)v0.y; o[2] = (__bf16)v0.z; o[3] = (__bf16)v0.w;
    o[4] = (__bf16)v1.x; o[5] = (__bf16)v1.y; o[6] = (__bf16)v1.z; o[7] = (__bf16)v1.w;
    *(bf16x8*)(dst + e) = o;
  }
}

// ---------------- bf16 GEMM, C = A * B^T  (round-10 8-phase, known-good) ---
// 256x256, BK=64, 512 thr (8 waves 2Mx4N), 128 KiB LDS. r11's 256x384
// attempt is DEAD: launch_bounds(512,4) capped VGPR at 128, acc[8][6]=192
// spilled (VGPR_Count=64, WRITE_SIZE 7.8GB). At 8 waves, per-wave output
// max is 128x64 (acc=128) -> 256x256 is the largest non-spilling tile.
template <typename OutT>
__global__ __launch_bounds__(512) void k_gemm8p(const __bf16* __restrict__ A,
                                                const __bf16* __restrict__ B,
                                                OutT* __restrict__ C,
                                                int M, int N, int K) {
  __shared__ __align__(16) __bf16 As[2][2][128 * 64];  // 64 KiB
  __shared__ __align__(16) __bf16 Bs[2][2][128 * 64];  // 64 KiB
  const int t = threadIdx.x;
  const int l = t & 63;
  const int w = t >> 6;
  const int wm = w >> 2;
  const int wn = w & 3;
  const int lr = l & 15, lg = l >> 4;
  const int sw = lr & 7;
  const int bm = blockIdx.y, bn = blockIdx.x;

  const int srow = t >> 3;
  const int scol = ((t & 7) ^ (srow & 7)) << 3;
  const __bf16* pa0 = A + (size_t)(bm * 256 +   0 + srow) * K + scol;
  const __bf16* pa1 = A + (size_t)(bm * 256 +  64 + srow) * K + scol;
  const __bf16* pa2 = A + (size_t)(bm * 256 + 128 + srow) * K + scol;
  const __bf16* pa3 = A + (size_t)(bm * 256 + 192 + srow) * K + scol;
  const __bf16* pb0 = B + (size_t)(bn * 256 +   0 + srow) * K + scol;
  const __bf16* pb1 = B + (size_t)(bn * 256 +  64 + srow) * K + scol;
  const __bf16* pb2 = B + (size_t)(bn * 256 + 128 + srow) * K + scol;
  const __bf16* pb3 = B + (size_t)(bn * 256 + 192 + srow) * K + scol;
  const int ldst = t * 8;

#define SA0(buf, kc) { gld_lds16(pa0 + (kc), &As[buf][0][ldst]); gld_lds16(pa1 + (kc), &As[buf][0][4096 + ldst]); }
#define SA1(buf, kc) { gld_lds16(pa2 + (kc), &As[buf][1][ldst]); gld_lds16(pa3 + (kc), &As[buf][1][4096 + ldst]); }
#define SB0(buf, kc) { gld_lds16(pb0 + (kc), &Bs[buf][0][ldst]); gld_lds16(pb1 + (kc), &Bs[buf][0][4096 + ldst]); }
#define SB1(buf, kc) { gld_lds16(pb2 + (kc), &Bs[buf][1][ldst]); gld_lds16(pb3 + (kc), &Bs[buf][1][4096 + ldst]); }

  const int c0 = ((lg ^ sw) * 8);
  const int c1 = (((lg ^ sw) ^ 4) * 8);
  const int aRow = lr;
  const int bRow = (wn & 1) * 64 + lr;

#define RDA(mi0, cur)                                                          \
  _Pragma("unroll") for (int mi = 0; mi < 4; ++mi) {                           \
    a[mi][0] = *(const bf16x8*)&As[cur][wm][(((mi0) + mi) * 16 + aRow) * 64 + c0]; \
    a[mi][1] = *(const bf16x8*)&As[cur][wm][(((mi0) + mi) * 16 + aRow) * 64 + c1]; \
  }
#define RDB(bv, ni0, cur)                                                      \
  _Pragma("unroll") for (int ni = 0; ni < 2; ++ni) {                           \
    bv[ni][0] = *(const bf16x8*)&Bs[cur][wn >> 1][(((ni0) + ni) * 16 + bRow) * 64 + c0]; \
    bv[ni][1] = *(const bf16x8*)&Bs[cur][wn >> 1][(((ni0) + ni) * 16 + bRow) * 64 + c1]; \
  }
#define PHTOP()                                        \
  asm volatile("" ::: "memory");                       \
  __builtin_amdgcn_s_barrier();                        \
  asm volatile("s_waitcnt lgkmcnt(0)" ::: "memory");   \
  __builtin_amdgcn_s_setprio(1)
#define PHEND()                                        \
  __builtin_amdgcn_s_setprio(0);                       \
  asm volatile("" ::: "memory");                       \
  __builtin_amdgcn_s_barrier()
#define PHENDW()                                       \
  __builtin_amdgcn_s_setprio(0);                       \
  asm volatile("s_waitcnt vmcnt(4)" ::: "memory");     \
  __builtin_amdgcn_s_barrier()
#define MMA16(am0, bv, ni0)                                                    \
  _Pragma("unroll") for (int mi = 0; mi < 4; ++mi)                             \
  _Pragma("unroll") for (int ni = 0; ni < 2; ++ni)                             \
  _Pragma("unroll") for (int kk = 0; kk < 2; ++kk)                             \
    acc[(am0) + mi][(ni0) + ni] = __builtin_amdgcn_mfma_f32_16x16x32_bf16(     \
        a[mi][kk], bv[ni][kk], acc[(am0) + mi][(ni0) + ni], 0, 0, 0);

  f32x4 acc[8][4] = {};
  const int nt = K >> 6;
  const int niter = nt >> 1;

  SB0(0, 0); SA0(0, 0); SA1(0, 0); SB1(0, 0);
  SB0(1, 64); SA0(1, 64);
  asm volatile("s_waitcnt vmcnt(4)" ::: "memory");
  asm volatile("" ::: "memory");
  __builtin_amdgcn_s_barrier();
  asm volatile("" ::: "memory");

  for (int i = 0; i < niter; ++i) {
    const int kT1 = (2 * i + 1) << 6;
    const int k2  = (2 * i + 2 < nt ? 2 * i + 2 : nt - 1) << 6;
    const int k3  = (2 * i + 3 < nt ? 2 * i + 3 : nt - 1) << 6;
    bf16x8 a[4][2], b0[2][2], b1[2][2];

    RDA(0, 0); RDB(b0, 0, 0);
    SA1(1, kT1);
    PHTOP(); MMA16(0, b0, 0); PHEND();
    RDB(b1, 2, 0);
    SB1(1, kT1);
    PHTOP(); MMA16(0, b1, 2); PHEND();
    RDA(4, 0);
    SB0(0, k2);
    PHTOP(); MMA16(4, b1, 2); PHEND();
    SA0(0, k2);
    PHTOP(); MMA16(4, b0, 0); PHENDW();

    RDA(0, 1); RDB(b0, 0, 1);
    SA1(0, k2);
    PHTOP(); MMA16(0, b0, 0); PHEND();
    RDB(b1, 2, 1);
    SB1(0, k2);
    PHTOP(); MMA16(0, b1, 2); PHEND();
    RDA(4, 1);
    SB0(1, k3);
    PHTOP(); MMA16(4, b1, 2); PHEND();
    SA0(1, k3);
    PHTOP(); MMA16(4, b0, 0); PHENDW();
  }
#undef SA0
#undef SA1
#undef SB0
#undef SB1
#undef RDA
#undef RDB
#undef PHTOP
#undef PHEND
#undef PHENDW
#undef MMA16

  const int row0 = bm * 256 + wm * 128;
  const int col0 = bn * 256 + wn * 64;
#pragma unroll
  for (int mi = 0; mi < 8; ++mi)
#pragma unroll
    for (int ni = 0; ni < 4; ++ni)
#pragma unroll
      for (int r = 0; r < 4; ++r)
        C[(size_t)(row0 + mi * 16 + lg * 4 + r) * N + (col0 + ni * 16 + lr)] =
            (OutT)acc[mi][ni][r];
}

// ---------------- fused RoPE + RMSNorm (in-place on Q and K regions) -------
__global__ __launch_bounds__(256) void k_rope_norm(__bf16* __restrict__ qkv,
                                                   const float* __restrict__ cosT,
                                                   const float* __restrict__ sinT) {
  const int task = blockIdx.x * 4 + (threadIdx.x >> 6);
  const int l = threadIdx.x & 63;
  const int m = task / 40;          // row in [0, 4096)
  const int h = task - m * 40;      // 0..31 = Q heads, 32..39 = K heads
  const int s = m & (SEQ - 1);
  const bool isQ = h < 32;
  const int col = isQ ? h * 128 : 4096 + (h - 32) * 128;
  __bf16* p = qkv + (size_t)m * QKVN + col + l * 2;
  float e = (float)p[0], o = (float)p[1];
  float c = cosT[s * 64 + l], sn = sinT[s * 64 + l];
  float e2 = e * c - o * sn;
  float o2 = e * sn + o * c;
  float ss = e2 * e2 + o2 * o2;
#pragma unroll
  for (int off = 32; off > 0; off >>= 1) ss += __shfl_xor(ss, off);
  float r = rsqrtf(ss * (1.0f / 128.0f) + 1e-5f);
  if (isQ) r *= 0.08838834764831845f;  // fold 1/sqrt(HEAD_DIM) into Q
  p[0] = (__bf16)(e2 * r);
  p[1] = (__bf16)(o2 * r);
}

// ---------------- V transpose: qkv V region (b,s,g,d) -> vt (b,g,d,s) ------
__global__ __launch_bounds__(256) void k_transpose_v(const __bf16* __restrict__ qkv,
                                                     __bf16* __restrict__ vt) {
  __shared__ __bf16 tile[64][136];  // padded row, no bank conflicts
  const int t = threadIdx.x;
  const int st = blockIdx.x, bg = blockIdx.y;
  const int b = bg >> 3, g = bg & 7;
  const int s0 = st * 64;
#pragma unroll
  for (int p = 0; p < 4; ++p) {
    int row = p * 16 + (t >> 4);
    int co = (t & 15) * 8;
    *(bf16x8*)&tile[row][co] =
        *(const bf16x8*)&qkv[(size_t)(b * SEQ + s0 + row) * QKVN + 5120 + g * 128 + co];
  }
  __syncthreads();
#pragma unroll
  for (int p = 0; p < 4; ++p) {
    int d = p * 32 + (t >> 3);
    int so = (t & 7) * 8;
    bf16x8 v;
#pragma unroll
    for (int j = 0; j < 8; ++j) v[j] = tile[so + j][d];
    *(bf16x8*)&vt[((size_t)bg * 128 + d) * SEQ + s0 + so] = v;
  }
}

// ---------------- causal flash attention (GQA) ------------------------------
// ROUND-12 CHANGE: K/V double-buffered with counted vmcnt (r7-proven
// pattern). Old: stage -> __syncthreads (vmcnt(0) drain!) -> compute = ~900cy
// exposed per kv-tile. New: stage KV(t+1)->buf^1 at top of iter t; vmcnt(8)
// retires KV(t) (issued a full iteration ago, ~free); raw s_barrier; compute
// from buf; end-barrier. Race-free: buf^1's reads ended at iter t-1's
// end-barrier; buf restaged (for t+2) only after iter t's end-barrier.
// Last iter: vmcnt(0), uniform across waves. LDS 72 KB -> 2 blocks/CU.
__global__ __launch_bounds__(256) void k_flash(const __bf16* __restrict__ qkv,
                                               const __bf16* __restrict__ vt,
                                               __bf16* __restrict__ attno) {
  __shared__ __bf16 Ks[2][64 * 128];   // [kv][d], swizzled   (32 KB)
  __shared__ __bf16 Vs[2][128 * 64];   // [d][kv], swizzled   (32 KB)
  __shared__ __bf16 Ps[4][16 * 64];    // per-wave [q][kv]    ( 8 KB)
  const int t = threadIdx.x, w = t >> 6, l = t & 63;
  const int lr = l & 15, lg = l >> 4;
  const int bh = blockIdx.y;        // b*32 + h
  const int b = bh >> 5, h = bh & 31, g = h >> 2;
  const int qt0 = blockIdx.x, qt1 = 31 - (int)blockIdx.x;

  const __bf16* kp = qkv + 4096 + (size_t)(b * SEQ + (t >> 4)) * QKVN + g * 128 +
                     (((t & 15) ^ ((t >> 4) & 7)) * 8);
  const __bf16* vp = vt + (size_t)(b * 8 + g) * 128 * SEQ + (size_t)(t >> 3) * SEQ +
                     (((t & 7) ^ ((t >> 3) & 7)) * 8);
  const int wbase = (t & ~63) * 8;
  const int sw = lr & 7;

#define STAGE_KV(buf, kv)                                                    \
  do {                                                                       \
    _Pragma("unroll") for (int i_ = 0; i_ < 4; ++i_)                         \
        gld_lds16(kp + ((kv) + i_ * 16) * QKVN, &Ks[buf][i_ * 2048 + wbase]);\
    _Pragma("unroll") for (int i_ = 0; i_ < 4; ++i_)                         \
        gld_lds16(vp + (size_t)(i_ * 32) * SEQ + (kv), &Vs[buf][i_ * 2048 + wbase]); \
  } while (0)

  for (int pass = 0; pass < 2; ++pass) {
    const int qt = (pass == 0) ? qt0 : qt1;

    const __bf16* Qb = qkv + (size_t)(b * SEQ + qt * 64 + w * 16 + lr) * QKVN + h * 128;
    bf16x8 qf[4];
#pragma unroll
    for (int kk = 0; kk < 4; ++kk) qf[kk] = *(const bf16x8*)&Qb[kk * 32 + lg * 8];

    f32x4 oacc[8] = {};
    float mrow[4], lsum[4];
#pragma unroll
    for (int r = 0; r < 4; ++r) { mrow[r] = -1e30f; lsum[r] = 0.f; }

    // prologue: stage tile 0 into buf 0 (8 loads in flight)
    STAGE_KV(0, (size_t)0);

    for (int kt = 0; kt <= qt; ++kt) {
      const int buf = kt & 1;
      if (kt < qt) {
        STAGE_KV(buf ^ 1, (size_t)(kt + 1) * 64);
        asm volatile("s_waitcnt vmcnt(8)" ::: "memory");  // KV(kt) landed (own)
      } else {
        asm volatile("s_waitcnt vmcnt(0)" ::: "memory");  // last tile (uniform)
      }
      asm volatile("" ::: "memory");
      __builtin_amdgcn_s_barrier();                       // ... for ALL waves
      asm volatile("" ::: "memory");

      // S = Q K^T
      f32x4 sc[4] = {};
      __builtin_amdgcn_s_setprio(1);
#pragma unroll
      for (int kk = 0; kk < 4; ++kk)
#pragma unroll
        for (int n = 0; n < 4; ++n) {
          bf16x8 kf = *(const bf16x8*)&Ks[buf][(n * 16 + lr) * 128 + ((kk * 4 + lg) ^ sw) * 8];
          sc[n] = __builtin_amdgcn_mfma_f32_16x16x32_bf16(qf[kk], kf, sc[n], 0, 0, 0);
        }
      __builtin_amdgcn_s_setprio(0);

      if (kt == qt) {  // diagonal tile: causal mask
#pragma unroll
        for (int n = 0; n < 4; ++n)
#pragma unroll
          for (int r = 0; r < 4; ++r)
            if (n * 16 + lr > w * 16 + lg * 4 + r) sc[n][r] = -1e30f;
      }

      // online softmax with defer-max (T13, THR=8)
      float pml[4];
      float need = -1e30f;
#pragma unroll
      for (int r = 0; r < 4; ++r) {
        pml[r] = fmaxf(fmaxf(sc[0][r], sc[1][r]), fmaxf(sc[2][r], sc[3][r]));
        need = fmaxf(need, pml[r] - mrow[r]);
      }
      if (__all(need <= 8.0f)) {
#pragma unroll
        for (int r = 0; r < 4; ++r) {
          float ps = 0.f;
#pragma unroll
          for (int n = 0; n < 4; ++n) { sc[n][r] = __expf(sc[n][r] - mrow[r]); ps += sc[n][r]; }
#pragma unroll
          for (int off = 8; off > 0; off >>= 1) ps += __shfl_xor(ps, off);
          lsum[r] += ps;
        }
      } else {
#pragma unroll
        for (int r = 0; r < 4; ++r) {
          float pm = pml[r];
#pragma unroll
          for (int off = 8; off > 0; off >>= 1) pm = fmaxf(pm, __shfl_xor(pm, off));
          float mn = fmaxf(mrow[r], pm);
          float corr = __expf(mrow[r] - mn);
          mrow[r] = mn;
          float ps = 0.f;
#pragma unroll
          for (int n = 0; n < 4; ++n) { sc[n][r] = __expf(sc[n][r] - mn); ps += sc[n][r]; }
#pragma unroll
          for (int off = 8; off > 0; off >>= 1) ps += __shfl_xor(ps, off);
          lsum[r] = lsum[r] * corr + ps;
#pragma unroll
          for (int dn = 0; dn < 8; ++dn) oacc[dn][r] *= corr;
        }
      }

      // P -> LDS (swizzled)
#pragma unroll
      for (int n = 0; n < 4; ++n)
#pragma unroll
        for (int r = 0; r < 4; ++r) {
          int row = lg * 4 + r;
          Ps[w][row * 64 + (((n * 2 + (lr >> 3)) ^ (row & 7)) * 8) + (lr & 7)] = (__bf16)sc[n][r];
        }

      // O += P V
      __builtin_amdgcn_s_setprio(1);
#pragma unroll
      for (int ks = 0; ks < 2; ++ks) {
        bf16x8 pf = *(const bf16x8*)&Ps[w][lr * 64 + ((ks * 4 + lg) ^ sw) * 8];
#pragma unroll
        for (int dn = 0; dn < 8; ++dn) {
          bf16x8 vf = *(const bf16x8*)&Vs[buf][(dn * 16 + lr) * 64 + ((ks * 4 + lg) ^ sw) * 8];
          oacc[dn] = __builtin_amdgcn_mfma_f32_16x16x32_bf16(pf, vf, oacc[dn], 0, 0, 0);
        }
      }
      __builtin_amdgcn_s_setprio(0);
      asm volatile("" ::: "memory");
      __builtin_amdgcn_s_barrier();   // reads of buf done before restage
      asm volatile("" ::: "memory");
    }

    float inv[4];
#pragma unroll
    for (int r = 0; r < 4; ++r) inv[r] = __builtin_amdgcn_rcpf(lsum[r]);
    __bf16* Ob = attno + (size_t)(b * SEQ + qt * 64 + w * 16) * DIMSZ + h * 128;
#pragma unroll
    for (int dn = 0; dn < 8; ++dn)
#pragma unroll
      for (int r = 0; r < 4; ++r)
        Ob[(size_t)(lg * 4 + r) * DIMSZ + dn * 16 + lr] = (__bf16)(oacc[dn][r] * inv[r]);
  }
#undef STAGE_KV
}

// ---------------- host launcher --------------------------------------------
extern "C" void kernel_launch(void* const* d_in, const int* in_sizes, int n_in,
                              void* d_out, int out_size, void* d_ws, size_t ws_size,
                              hipStream_t stream) {
  const float* x    = (const float*)d_in[0];
  const float* wq   = (const float*)d_in[1];
  const float* wk   = (const float*)d_in[2];
  const float* wv   = (const float*)d_in[3];
  const float* wo   = (const float*)d_in[4];
  const float* cosT = (const float*)d_in[5];
  const float* sinT = (const float*)d_in[6];
  // d_in[7] (mask) implemented as causal; d_in[8] (start_pos) == 0.

  char* ws = (char*)d_ws;
  __bf16* xb    = (__bf16*)(ws);                    // 4096x4096        (32 MiB)
  __bf16* wqkvb = (__bf16*)(ws + 33554432);         // 6144x4096        (48 MiB)
  __bf16* qkvb  = (__bf16*)(ws + 83886080);         // 4096x6144        (48 MiB)
  __bf16* wob   = (__bf16*)(ws + 134217728);        // 4096x4096        (32 MiB)
  __bf16* vt    = (__bf16*)(ws + 167772160);        // 16x128x2048      ( 8 MiB)
  __bf16* attno = (__bf16*)(ws + 176160768);        // 4096x4096        (32 MiB)
  float* out = (float*)d_out;

  // fp32 -> bf16 conversions, single merged launch
  k_cvt5<<<4096, 256, 0, stream>>>(x, wq, wk, wv, wo, xb, wqkvb, wob);

  // QKV projection: M=4096, N=6144 -> grid (24, 16), bn fastest
  k_gemm8p<__bf16><<<dim3(24, 16), 512, 0, stream>>>(xb, wqkvb, qkvb, 4096, QKVN, 4096);
  // RoPE + RMSNorm on Q,K (in place), attention scale folded into Q
  k_rope_norm<<<40960, 256, 0, stream>>>(qkvb, cosT, sinT);
  // V -> V^T for contiguous PV operand reads
  k_transpose_v<<<dim3(32, 16), 256, 0, stream>>>(qkvb, vt);
  // causal GQA flash attention (paired q-tiles, double-buffered KV)
  k_flash<<<dim3(16, 64), 256, 0, stream>>>(qkvb, vt, attno);
  // output projection: M=4096, N=4096 -> grid (16, 16)
  k_gemm8p<float><<<dim3(16, 16), 512, 0, stream>>>(attno, wob, out, 4096, DIMSZ, 4096);
}

// Round 13
// 598.792 us; speedup vs baseline: 5.1123x; 1.1655x over previous
//
#include <hip/hip_runtime.h>
#include <hip/hip_bf16.h>
#include <stdint.h>

#define SEQ 2048
#define DIMSZ 4096
#define QKVN 6144   // 4096 Q + 1024 K + 1024 V

typedef __attribute__((ext_vector_type(8))) __bf16 bf16x8;
typedef __attribute__((ext_vector_type(4))) float f32x4;

// async global->LDS, 16B per lane; dest = wave-uniform base + lane*16
static __device__ __forceinline__ void gld_lds16(const void* g, void* l) {
  __builtin_amdgcn_global_load_lds(
      (__attribute__((address_space(1))) void*)(g),
      (__attribute__((address_space(3))) void*)(l), 16, 0, 0);
}

// ---------------- merged fp32 -> bf16 conversion (one launch, 5 segments) --
__global__ __launch_bounds__(256) void k_cvt5(const float* __restrict__ x,
                                              const float* __restrict__ wq,
                                              const float* __restrict__ wk,
                                              const float* __restrict__ wv,
                                              const float* __restrict__ wo,
                                              __bf16* __restrict__ xb,
                                              __bf16* __restrict__ wqkvb,
                                              __bf16* __restrict__ wob) {
  long vid = (long)blockIdx.x * 256 + threadIdx.x;
  const long stride = (long)gridDim.x * 256;
  for (; vid < 7340032L; vid += stride) {
    const float* src; __bf16* dst; long off;
    if (vid < 2097152L)      { src = x;  dst = xb;                off = vid; }
    else if (vid < 4194304L) { src = wq; dst = wqkvb;             off = vid - 2097152L; }
    else if (vid < 4718592L) { src = wk; dst = wqkvb + 16777216L; off = vid - 4194304L; }
    else if (vid < 5242880L) { src = wv; dst = wqkvb + 20971520L; off = vid - 4718592L; }
    else                     { src = wo; dst = wob;               off = vid - 5242880L; }
    const long e = off * 8;
    float4 v0 = *(const float4*)(src + e);
    float4 v1 = *(const float4*)(src + e + 4);
    bf16x8 o;
    o[0] = (__bf16)v0.x; o[1] = (__bf16)v0.y; o[2] = (__bf16)v0.z; o[3] = (__bf16)v0.w;
    o[4] = (__bf16)v1.x; o[5] = (__bf16)v1.y; o[6] = (__bf16)v1.z; o[7] = (__bf16)v1.w;
    *(bf16x8*)(dst + e) = o;
  }
}

// ---------------- bf16 GEMM, C = A * B^T  (8-phase, ROUND-13 re-stagger) ---
// 256x256, BK=64, 512 thr (8 waves 2Mx4N), 128 KiB LDS.
// r10 stagger gave T1's B1-half only a 2-phase (~500cy) lead vs ~900cy HBM
// -> the ph3/ph7 vmcnt stalled. New stagger (earliest-legal placement):
//   ph2: B0+B1(T0+2)  (buf-cur B reads end ph1 + barrier)
//   ph3: A0+A1(T0+2)  (buf-cur A reads end ph2 + barrier)
//   ph6: B0+B1(T1+2)  (buf-nxt B reads end ph5 + barrier)
//   ph7: A0+A1(T1+2)  (buf-nxt A reads end ph6 + barrier)
// Every half-tile now has a 5-6 phase (~1300cy) lead. vmcnt(8) at ph3/ph7:
// at ph3 end outstanding = ph2(4)+ph3(4) = 8 -> retires prev ph6/ph7 = all
// of T1 exactly; symmetric at ph7 (retires T0+2, staged ph2/ph3). Prologue
// stages T0(8)+T1(8), vmcnt(8) retires T0. Counted, never 0.
template <typename OutT>
__global__ __launch_bounds__(512) void k_gemm8p(const __bf16* __restrict__ A,
                                                const __bf16* __restrict__ B,
                                                OutT* __restrict__ C,
                                                int M, int N, int K) {
  __shared__ __align__(16) __bf16 As[2][2][128 * 64];  // 64 KiB
  __shared__ __align__(16) __bf16 Bs[2][2][128 * 64];  // 64 KiB
  const int t = threadIdx.x;
  const int l = t & 63;
  const int w = t >> 6;
  const int wm = w >> 2;
  const int wn = w & 3;
  const int lr = l & 15, lg = l >> 4;
  const int sw = lr & 7;
  const int bm = blockIdx.y, bn = blockIdx.x;

  const int srow = t >> 3;
  const int scol = ((t & 7) ^ (srow & 7)) << 3;
  const __bf16* pa0 = A + (size_t)(bm * 256 +   0 + srow) * K + scol;
  const __bf16* pa1 = A + (size_t)(bm * 256 +  64 + srow) * K + scol;
  const __bf16* pa2 = A + (size_t)(bm * 256 + 128 + srow) * K + scol;
  const __bf16* pa3 = A + (size_t)(bm * 256 + 192 + srow) * K + scol;
  const __bf16* pb0 = B + (size_t)(bn * 256 +   0 + srow) * K + scol;
  const __bf16* pb1 = B + (size_t)(bn * 256 +  64 + srow) * K + scol;
  const __bf16* pb2 = B + (size_t)(bn * 256 + 128 + srow) * K + scol;
  const __bf16* pb3 = B + (size_t)(bn * 256 + 192 + srow) * K + scol;
  const int ldst = t * 8;

#define SA0(buf, kc) { gld_lds16(pa0 + (kc), &As[buf][0][ldst]); gld_lds16(pa1 + (kc), &As[buf][0][4096 + ldst]); }
#define SA1(buf, kc) { gld_lds16(pa2 + (kc), &As[buf][1][ldst]); gld_lds16(pa3 + (kc), &As[buf][1][4096 + ldst]); }
#define SB0(buf, kc) { gld_lds16(pb0 + (kc), &Bs[buf][0][ldst]); gld_lds16(pb1 + (kc), &Bs[buf][0][4096 + ldst]); }
#define SB1(buf, kc) { gld_lds16(pb2 + (kc), &Bs[buf][1][ldst]); gld_lds16(pb3 + (kc), &Bs[buf][1][4096 + ldst]); }

  const int c0 = ((lg ^ sw) * 8);
  const int c1 = (((lg ^ sw) ^ 4) * 8);
  const int aRow = lr;
  const int bRow = (wn & 1) * 64 + lr;

#define RDA(mi0, cur)                                                          \
  _Pragma("unroll") for (int mi = 0; mi < 4; ++mi) {                           \
    a[mi][0] = *(const bf16x8*)&As[cur][wm][(((mi0) + mi) * 16 + aRow) * 64 + c0]; \
    a[mi][1] = *(const bf16x8*)&As[cur][wm][(((mi0) + mi) * 16 + aRow) * 64 + c1]; \
  }
#define RDB(bv, ni0, cur)                                                      \
  _Pragma("unroll") for (int ni = 0; ni < 2; ++ni) {                           \
    bv[ni][0] = *(const bf16x8*)&Bs[cur][wn >> 1][(((ni0) + ni) * 16 + bRow) * 64 + c0]; \
    bv[ni][1] = *(const bf16x8*)&Bs[cur][wn >> 1][(((ni0) + ni) * 16 + bRow) * 64 + c1]; \
  }
#define PHTOP()                                        \
  asm volatile("" ::: "memory");                       \
  __builtin_amdgcn_s_barrier();                        \
  asm volatile("s_waitcnt lgkmcnt(0)" ::: "memory");   \
  __builtin_amdgcn_s_setprio(1)
#define PHEND()                                        \
  __builtin_amdgcn_s_setprio(0);                       \
  asm volatile("" ::: "memory");                       \
  __builtin_amdgcn_s_barrier()
#define PHENDW()                                       \
  __builtin_amdgcn_s_setprio(0);                       \
  asm volatile("s_waitcnt vmcnt(8)" ::: "memory");     \
  __builtin_amdgcn_s_barrier()
#define MMA16(am0, bv, ni0)                                                    \
  _Pragma("unroll") for (int mi = 0; mi < 4; ++mi)                             \
  _Pragma("unroll") for (int ni = 0; ni < 2; ++ni)                             \
  _Pragma("unroll") for (int kk = 0; kk < 2; ++kk)                             \
    acc[(am0) + mi][(ni0) + ni] = __builtin_amdgcn_mfma_f32_16x16x32_bf16(     \
        a[mi][kk], bv[ni][kk], acc[(am0) + mi][(ni0) + ni], 0, 0, 0);

  f32x4 acc[8][4] = {};
  const int nt = K >> 6;        // K-tiles (64 for K=4096), even
  const int niter = nt >> 1;

  // prologue: T0 (8 loads) then T1 (8 loads); vmcnt(8) retires T0
  {
    const int k1 = (nt > 1 ? 1 : 0) << 6;
    SB0(0, 0); SB1(0, 0); SA0(0, 0); SA1(0, 0);
    SB0(1, k1); SB1(1, k1); SA0(1, k1); SA1(1, k1);
  }
  asm volatile("s_waitcnt vmcnt(8)" ::: "memory");
  asm volatile("" ::: "memory");
  __builtin_amdgcn_s_barrier();
  asm volatile("" ::: "memory");

  for (int i = 0; i < niter; ++i) {
    const int k2 = (2 * i + 2 < nt ? 2 * i + 2 : nt - 1) << 6;
    const int k3 = (2 * i + 3 < nt ? 2 * i + 3 : nt - 1) << 6;
    bf16x8 a[4][2], b0[2][2], b1[2][2];

    // ---- ph0: T0 a03 x b01 ----
    RDA(0, 0); RDB(b0, 0, 0);
    PHTOP(); MMA16(0, b0, 0); PHEND();
    // ---- ph1: T0 a03 x b23 (B(T0) LDS reads end here) ----
    RDB(b1, 2, 0);
    PHTOP(); MMA16(0, b1, 2); PHEND();
    // ---- ph2: T0 a47 x b23 (A(T0) LDS reads end); stage B(T0+2) ----
    RDA(4, 0);
    SB0(0, k2); SB1(0, k2);
    PHTOP(); MMA16(4, b1, 2); PHEND();
    // ---- ph3: T0 a47 x b01 (regs); stage A(T0+2); retire T1 ----
    SA0(0, k2); SA1(0, k2);
    PHTOP(); MMA16(4, b0, 0); PHENDW();

    // ---- ph4: T1 a03 x b01 ----
    RDA(0, 1); RDB(b0, 0, 1);
    PHTOP(); MMA16(0, b0, 0); PHEND();
    // ---- ph5: T1 a03 x b23 (B(T1) LDS reads end) ----
    RDB(b1, 2, 1);
    PHTOP(); MMA16(0, b1, 2); PHEND();
    // ---- ph6: T1 a47 x b23 (A(T1) LDS reads end); stage B(T1+2) ----
    RDA(4, 1);
    SB0(1, k3); SB1(1, k3);
    PHTOP(); MMA16(4, b1, 2); PHEND();
    // ---- ph7: T1 a47 x b01 (regs); stage A(T1+2); retire T0+2 ----
    SA0(1, k3); SA1(1, k3);
    PHTOP(); MMA16(4, b0, 0); PHENDW();
  }
#undef SA0
#undef SA1
#undef SB0
#undef SB1
#undef RDA
#undef RDB
#undef PHTOP
#undef PHEND
#undef PHENDW
#undef MMA16

  const int row0 = bm * 256 + wm * 128;
  const int col0 = bn * 256 + wn * 64;
#pragma unroll
  for (int mi = 0; mi < 8; ++mi)
#pragma unroll
    for (int ni = 0; ni < 4; ++ni)
#pragma unroll
      for (int r = 0; r < 4; ++r)
        C[(size_t)(row0 + mi * 16 + lg * 4 + r) * N + (col0 + ni * 16 + lr)] =
            (OutT)acc[mi][ni][r];
}

// ---------------- fused RoPE + RMSNorm (in-place on Q and K regions) -------
__global__ __launch_bounds__(256) void k_rope_norm(__bf16* __restrict__ qkv,
                                                   const float* __restrict__ cosT,
                                                   const float* __restrict__ sinT) {
  const int task = blockIdx.x * 4 + (threadIdx.x >> 6);
  const int l = threadIdx.x & 63;
  const int m = task / 40;          // row in [0, 4096)
  const int h = task - m * 40;      // 0..31 = Q heads, 32..39 = K heads
  const int s = m & (SEQ - 1);
  const bool isQ = h < 32;
  const int col = isQ ? h * 128 : 4096 + (h - 32) * 128;
  __bf16* p = qkv + (size_t)m * QKVN + col + l * 2;
  float e = (float)p[0], o = (float)p[1];
  float c = cosT[s * 64 + l], sn = sinT[s * 64 + l];
  float e2 = e * c - o * sn;
  float o2 = e * sn + o * c;
  float ss = e2 * e2 + o2 * o2;
#pragma unroll
  for (int off = 32; off > 0; off >>= 1) ss += __shfl_xor(ss, off);
  float r = rsqrtf(ss * (1.0f / 128.0f) + 1e-5f);
  if (isQ) r *= 0.08838834764831845f;  // fold 1/sqrt(HEAD_DIM) into Q
  p[0] = (__bf16)(e2 * r);
  p[1] = (__bf16)(o2 * r);
}

// ---------------- V transpose: qkv V region (b,s,g,d) -> vt (b,g,d,s) ------
__global__ __launch_bounds__(256) void k_transpose_v(const __bf16* __restrict__ qkv,
                                                     __bf16* __restrict__ vt) {
  __shared__ __bf16 tile[64][136];  // padded row, no bank conflicts
  const int t = threadIdx.x;
  const int st = blockIdx.x, bg = blockIdx.y;
  const int b = bg >> 3, g = bg & 7;
  const int s0 = st * 64;
#pragma unroll
  for (int p = 0; p < 4; ++p) {
    int row = p * 16 + (t >> 4);
    int co = (t & 15) * 8;
    *(bf16x8*)&tile[row][co] =
        *(const bf16x8*)&qkv[(size_t)(b * SEQ + s0 + row) * QKVN + 5120 + g * 128 + co];
  }
  __syncthreads();
#pragma unroll
  for (int p = 0; p < 4; ++p) {
    int d = p * 32 + (t >> 3);
    int so = (t & 7) * 8;
    bf16x8 v;
#pragma unroll
    for (int j = 0; j < 8; ++j) v[j] = tile[so + j][d];
    *(bf16x8*)&vt[((size_t)bg * 128 + d) * SEQ + s0 + so] = v;
  }
}

// ---------------- causal flash attention (GQA) — round-9 version (revert) --
// r12's KV double-buffer REVERTED: 72KB LDS halved blocks/CU 4->2 and flash
// is TLP-bound (267 vs 120 µs ≈ the occupancy ratio). Single-buffer 40KB,
// 4 blocks/CU; cross-block overlap hides the staging drain (T14 lesson).
__global__ __launch_bounds__(256) void k_flash(const __bf16* __restrict__ qkv,
                                               const __bf16* __restrict__ vt,
                                               __bf16* __restrict__ attno) {
  __shared__ __bf16 Ks[64 * 128];   // [kv][d], swizzled
  __shared__ __bf16 Vs[128 * 64];   // [d][kv], swizzled
  __shared__ __bf16 Ps[4][16 * 64]; // per-wave [q][kv], swizzled
  const int t = threadIdx.x, w = t >> 6, l = t & 63;
  const int lr = l & 15, lg = l >> 4;
  const int bh = blockIdx.y;        // b*32 + h
  const int b = bh >> 5, h = bh & 31, g = h >> 2;
  const int qt0 = blockIdx.x, qt1 = 31 - (int)blockIdx.x;

  const __bf16* kp = qkv + 4096 + (size_t)(b * SEQ + (t >> 4)) * QKVN + g * 128 +
                     (((t & 15) ^ ((t >> 4) & 7)) * 8);
  const __bf16* vp = vt + (size_t)(b * 8 + g) * 128 * SEQ + (size_t)(t >> 3) * SEQ +
                     (((t & 7) ^ ((t >> 3) & 7)) * 8);
  const int wbase = (t & ~63) * 8;
  const int sw = lr & 7;

  for (int pass = 0; pass < 2; ++pass) {
    const int qt = (pass == 0) ? qt0 : qt1;

    const __bf16* Qb = qkv + (size_t)(b * SEQ + qt * 64 + w * 16 + lr) * QKVN + h * 128;
    bf16x8 qf[4];
#pragma unroll
    for (int kk = 0; kk < 4; ++kk) qf[kk] = *(const bf16x8*)&Qb[kk * 32 + lg * 8];

    f32x4 oacc[8] = {};
    float mrow[4], lsum[4];
#pragma unroll
    for (int r = 0; r < 4; ++r) { mrow[r] = -1e30f; lsum[r] = 0.f; }

    for (int kt = 0; kt <= qt; ++kt) {
      const size_t kv0 = (size_t)kt * 64;
#pragma unroll
      for (int i = 0; i < 4; ++i)
        gld_lds16(kp + (kv0 + i * 16) * QKVN, &Ks[i * 2048 + wbase]);
#pragma unroll
      for (int i = 0; i < 4; ++i)
        gld_lds16(vp + (size_t)i * 32 * SEQ + kv0, &Vs[i * 2048 + wbase]);
      __syncthreads();

      // S = Q K^T
      f32x4 sc[4] = {};
      __builtin_amdgcn_s_setprio(1);
#pragma unroll
      for (int kk = 0; kk < 4; ++kk)
#pragma unroll
        for (int n = 0; n < 4; ++n) {
          bf16x8 kf = *(const bf16x8*)&Ks[(n * 16 + lr) * 128 + ((kk * 4 + lg) ^ sw) * 8];
          sc[n] = __builtin_amdgcn_mfma_f32_16x16x32_bf16(qf[kk], kf, sc[n], 0, 0, 0);
        }
      __builtin_amdgcn_s_setprio(0);

      if (kt == qt) {  // diagonal tile: causal mask
#pragma unroll
        for (int n = 0; n < 4; ++n)
#pragma unroll
          for (int r = 0; r < 4; ++r)
            if (n * 16 + lr > w * 16 + lg * 4 + r) sc[n][r] = -1e30f;
      }

      // online softmax with defer-max (T13, THR=8)
      float pml[4];
      float need = -1e30f;
#pragma unroll
      for (int r = 0; r < 4; ++r) {
        pml[r] = fmaxf(fmaxf(sc[0][r], sc[1][r]), fmaxf(sc[2][r], sc[3][r]));
        need = fmaxf(need, pml[r] - mrow[r]);
      }
      if (__all(need <= 8.0f)) {
#pragma unroll
        for (int r = 0; r < 4; ++r) {
          float ps = 0.f;
#pragma unroll
          for (int n = 0; n < 4; ++n) { sc[n][r] = __expf(sc[n][r] - mrow[r]); ps += sc[n][r]; }
#pragma unroll
          for (int off = 8; off > 0; off >>= 1) ps += __shfl_xor(ps, off);
          lsum[r] += ps;
        }
      } else {
#pragma unroll
        for (int r = 0; r < 4; ++r) {
          float pm = pml[r];
#pragma unroll
          for (int off = 8; off > 0; off >>= 1) pm = fmaxf(pm, __shfl_xor(pm, off));
          float mn = fmaxf(mrow[r], pm);
          float corr = __expf(mrow[r] - mn);
          mrow[r] = mn;
          float ps = 0.f;
#pragma unroll
          for (int n = 0; n < 4; ++n) { sc[n][r] = __expf(sc[n][r] - mn); ps += sc[n][r]; }
#pragma unroll
          for (int off = 8; off > 0; off >>= 1) ps += __shfl_xor(ps, off);
          lsum[r] = lsum[r] * corr + ps;
#pragma unroll
          for (int dn = 0; dn < 8; ++dn) oacc[dn][r] *= corr;
        }
      }

      // P -> LDS (swizzled)
#pragma unroll
      for (int n = 0; n < 4; ++n)
#pragma unroll
        for (int r = 0; r < 4; ++r) {
          int row = lg * 4 + r;
          Ps[w][row * 64 + (((n * 2 + (lr >> 3)) ^ (row & 7)) * 8) + (lr & 7)] = (__bf16)sc[n][r];
        }

      // O += P V
      __builtin_amdgcn_s_setprio(1);
#pragma unroll
      for (int ks = 0; ks < 2; ++ks) {
        bf16x8 pf = *(const bf16x8*)&Ps[w][lr * 64 + ((ks * 4 + lg) ^ sw) * 8];
#pragma unroll
        for (int dn = 0; dn < 8; ++dn) {
          bf16x8 vf = *(const bf16x8*)&Vs[(dn * 16 + lr) * 64 + ((ks * 4 + lg) ^ sw) * 8];
          oacc[dn] = __builtin_amdgcn_mfma_f32_16x16x32_bf16(pf, vf, oacc[dn], 0, 0, 0);
        }
      }
      __builtin_amdgcn_s_setprio(0);
      __syncthreads();
    }

    float inv[4];
#pragma unroll
    for (int r = 0; r < 4; ++r) inv[r] = __builtin_amdgcn_rcpf(lsum[r]);
    __bf16* Ob = attno + (size_t)(b * SEQ + qt * 64 + w * 16) * DIMSZ + h * 128;
#pragma unroll
    for (int dn = 0; dn < 8; ++dn)
#pragma unroll
      for (int r = 0; r < 4; ++r)
        Ob[(size_t)(lg * 4 + r) * DIMSZ + dn * 16 + lr] = (__bf16)(oacc[dn][r] * inv[r]);
  }
}

// ---------------- host launcher --------------------------------------------
extern "C" void kernel_launch(void* const* d_in, const int* in_sizes, int n_in,
                              void* d_out, int out_size, void* d_ws, size_t ws_size,
                              hipStream_t stream) {
  const float* x    = (const float*)d_in[0];
  const float* wq   = (const float*)d_in[1];
  const float* wk   = (const float*)d_in[2];
  const float* wv   = (const float*)d_in[3];
  const float* wo   = (const float*)d_in[4];
  const float* cosT = (const float*)d_in[5];
  const float* sinT = (const float*)d_in[6];
  // d_in[7] (mask) implemented as causal; d_in[8] (start_pos) == 0.

  char* ws = (char*)d_ws;
  __bf16* xb    = (__bf16*)(ws);                    // 4096x4096        (32 MiB)
  __bf16* wqkvb = (__bf16*)(ws + 33554432);         // 6144x4096        (48 MiB)
  __bf16* qkvb  = (__bf16*)(ws + 83886080);         // 4096x6144        (48 MiB)
  __bf16* wob   = (__bf16*)(ws + 134217728);        // 4096x4096        (32 MiB)
  __bf16* vt    = (__bf16*)(ws + 167772160);        // 16x128x2048      ( 8 MiB)
  __bf16* attno = (__bf16*)(ws + 176160768);        // 4096x4096        (32 MiB)
  float* out = (float*)d_out;

  // fp32 -> bf16 conversions, single merged launch
  k_cvt5<<<4096, 256, 0, stream>>>(x, wq, wk, wv, wo, xb, wqkvb, wob);

  // QKV projection: M=4096, N=6144 -> grid (24, 16), bn fastest
  k_gemm8p<__bf16><<<dim3(24, 16), 512, 0, stream>>>(xb, wqkvb, qkvb, 4096, QKVN, 4096);
  // RoPE + RMSNorm on Q,K (in place), attention scale folded into Q
  k_rope_norm<<<40960, 256, 0, stream>>>(qkvb, cosT, sinT);
  // V -> V^T for contiguous PV operand reads
  k_transpose_v<<<dim3(32, 16), 256, 0, stream>>>(qkvb, vt);
  // causal GQA flash attention (paired q-tiles, single-buffer KV — r9)
  k_flash<<<dim3(16, 64), 256, 0, stream>>>(qkvb, vt, attno);
  // output projection: M=4096, N=4096 -> grid (16, 16)
  k_gemm8p<float><<<dim3(16, 16), 512, 0, stream>>>(attno, wob, out, 4096, DIMSZ, 4096);
}

// Round 14
// 586.351 us; speedup vs baseline: 5.2208x; 1.0212x over previous
//
#include <hip/hip_runtime.h>
#include <hip/hip_bf16.h>
#include <stdint.h>

#define SEQ 2048
#define DIMSZ 4096
#define QKVN 6144   // 4096 Q + 1024 K + 1024 V

typedef __attribute__((ext_vector_type(8))) __bf16 bf16x8;
typedef __attribute__((ext_vector_type(4))) float f32x4;

// async global->LDS, 16B per lane; dest = wave-uniform base + lane*16
static __device__ __forceinline__ void gld_lds16(const void* g, void* l) {
  __builtin_amdgcn_global_load_lds(
      (__attribute__((address_space(1))) void*)(g),
      (__attribute__((address_space(3))) void*)(l), 16, 0, 0);
}

// ---------------- merged fp32 -> bf16 conversion (one launch, 5 segments) --
__global__ __launch_bounds__(256) void k_cvt5(const float* __restrict__ x,
                                              const float* __restrict__ wq,
                                              const float* __restrict__ wk,
                                              const float* __restrict__ wv,
                                              const float* __restrict__ wo,
                                              __bf16* __restrict__ xb,
                                              __bf16* __restrict__ wqkvb,
                                              __bf16* __restrict__ wob) {
  long vid = (long)blockIdx.x * 256 + threadIdx.x;
  const long stride = (long)gridDim.x * 256;
  for (; vid < 7340032L; vid += stride) {
    const float* src; __bf16* dst; long off;
    if (vid < 2097152L)      { src = x;  dst = xb;                off = vid; }
    else if (vid < 4194304L) { src = wq; dst = wqkvb;             off = vid - 2097152L; }
    else if (vid < 4718592L) { src = wk; dst = wqkvb + 16777216L; off = vid - 4194304L; }
    else if (vid < 5242880L) { src = wv; dst = wqkvb + 20971520L; off = vid - 4718592L; }
    else                     { src = wo; dst = wob;               off = vid - 5242880L; }
    const long e = off * 8;
    float4 v0 = *(const float4*)(src + e);
    float4 v1 = *(const float4*)(src + e + 4);
    bf16x8 o;
    o[0] = (__bf16)v0.x; o[1] = (__bf16)v0.y; o[2] = (__bf16)v0.z; o[3] = (__bf16)v0.w;
    o[4] = (__bf16)v1.x; o[5] = (__bf16)v1.y; o[6] = (__bf16)v1.z; o[7] = (__bf16)v1.w;
    *(bf16x8*)(dst + e) = o;
  }
}

// ---------------- GEMM1: C = A*B^T, 128x256 tile, BK=64, triple-buffer -----
// r13 PM: GEMM is LDS-read-BW-bound per block; remaining recoverable loss is
// grid packing (384 blocks @1/CU = 2 serial rounds = 241 µs vs ideal 1.5T).
// 128x256 -> grid (24,32) = 768 blocks = EXACTLY 3 full rounds, zero tail.
// 8 waves (2M x 4N), wave-tile 64x64, acc[4][4]=64 VGPR (no r11 spill).
// LDS As[3][128x64] 48KB + Bs[3][256x64] 96KB = 144KB (1 block/CU).
// Tile U uses buf U%3; stage tile U+2 into buf (U+2)%3 (= buf of U-1, whose
// reads ended >=2 phases earlier -> race-free). Per tile, 2 phases:
//  ph0: ds_read a[0..3]x2kk (8) + b[0..1]x2kk (4); SA(U+2) [2 gld];
//       bar; lgkmcnt(0); prio1; 16 MFMA (a x b01); prio0; bar
//  ph1: ds_read b[2..3]x2kk (4); SB(U+2) [4 gld];
//       bar; lgkmcnt(0); prio1; 16 MFMA (a x b23); prio0;
//       s_waitcnt vmcnt(6); bar     <- counted, never 0:
// queue at ph1(U) end = [A(U+1)2, B(U+1)4, A(U+2)2, B(U+2)4] -> retire 6,
// keep 6. Leads: A 3-4 phases, B 2 phases of wall time (>= 2000 cy >> HBM).
// T2 swizzle: 16B chunk ^= row&7, pre-swizzled source (0 conflicts r5-r13).
__global__ __launch_bounds__(512) void k_gemm128x256(const __bf16* __restrict__ A,
                                                     const __bf16* __restrict__ B,
                                                     __bf16* __restrict__ C,
                                                     int M, int N, int K) {
  __shared__ __align__(16) __bf16 As[3][128 * 64];  // 48 KB
  __shared__ __align__(16) __bf16 Bs[3][256 * 64];  // 96 KB
  const int t = threadIdx.x;
  const int l = t & 63;
  const int w = t >> 6;        // 0..7
  const int wm = w >> 2;       // 0..1 : rows wm*64..+64
  const int wn = w & 3;        // 0..3 : cols wn*64..+64
  const int lr = l & 15, lg = l >> 4;
  const int sw = lr & 7;       // read-side chunk XOR
  const int bm = blockIdx.y, bn = blockIdx.x;

  // staging: one gld_lds issue = 512 thr x 16B = 64 rows x 64 cols
  const int srow = t >> 3;
  const int scol = ((t & 7) ^ (srow & 7)) << 3;
  const __bf16* pa0 = A + (size_t)(bm * 128 +   0 + srow) * K + scol;
  const __bf16* pa1 = A + (size_t)(bm * 128 +  64 + srow) * K + scol;
  const __bf16* pb0 = B + (size_t)(bn * 256 +   0 + srow) * K + scol;
  const __bf16* pb1 = B + (size_t)(bn * 256 +  64 + srow) * K + scol;
  const __bf16* pb2 = B + (size_t)(bn * 256 + 128 + srow) * K + scol;
  const __bf16* pb3 = B + (size_t)(bn * 256 + 192 + srow) * K + scol;
  const int ldst = t * 8;

#define SA(buf, kc) { gld_lds16(pa0 + (kc), &As[buf][ldst]);        \
                      gld_lds16(pa1 + (kc), &As[buf][4096 + ldst]); }
#define SB(buf, kc) { gld_lds16(pb0 + (kc), &Bs[buf][ldst]);        \
                      gld_lds16(pb1 + (kc), &Bs[buf][4096 + ldst]); \
                      gld_lds16(pb2 + (kc), &Bs[buf][8192 + ldst]); \
                      gld_lds16(pb3 + (kc), &Bs[buf][12288 + ldst]); }

  const int c0 = ((lg ^ sw) * 8);          // kk=0 chunk (elems)
  const int c1 = (((lg ^ sw) ^ 4) * 8);    // kk=1 (lg+4 == lg^4)
  const int aBase = wm * 4096 + lr * 64;   // + mi*1024 + ckk
  const int bBase = wn * 4096 + lr * 64;   // + ni*1024 + ckk

#define PHTOP()                                        \
  asm volatile("" ::: "memory");                       \
  __builtin_amdgcn_s_barrier();                        \
  asm volatile("s_waitcnt lgkmcnt(0)" ::: "memory");   \
  __builtin_amdgcn_s_setprio(1)
#define PHEND()                                        \
  __builtin_amdgcn_s_setprio(0);                       \
  asm volatile("" ::: "memory");                       \
  __builtin_amdgcn_s_barrier()
#define PHENDW()                                       \
  __builtin_amdgcn_s_setprio(0);                       \
  asm volatile("s_waitcnt vmcnt(6)" ::: "memory");     \
  __builtin_amdgcn_s_barrier()

  f32x4 acc[4][4] = {};
  const int nt = K >> 6;        // 64 K-tiles

  // prologue: tile0 (A2+B4) then tile1 (A2+B4); vmcnt(6) retires tile0
  SA(0, 0); SB(0, 0);
  SA(1, 64); SB(1, 64);
  asm volatile("s_waitcnt vmcnt(6)" ::: "memory");
  asm volatile("" ::: "memory");
  __builtin_amdgcn_s_barrier();
  asm volatile("" ::: "memory");

  int bu = 0, bu2 = 2;          // buf of tile U, buf of tile U+2
  for (int U = 0; U < nt; ++U) {
    const int kc = (U + 2 < nt ? U + 2 : nt - 1) << 6;
    bf16x8 a[4][2], b[2][2];

    // ---- ph0: a(all) x b01; stage A(U+2) ----
#pragma unroll
    for (int mi = 0; mi < 4; ++mi) {
      a[mi][0] = *(const bf16x8*)&As[bu][aBase + mi * 1024 + c0];
      a[mi][1] = *(const bf16x8*)&As[bu][aBase + mi * 1024 + c1];
    }
#pragma unroll
    for (int ni = 0; ni < 2; ++ni) {
      b[ni][0] = *(const bf16x8*)&Bs[bu][bBase + ni * 1024 + c0];
      b[ni][1] = *(const bf16x8*)&Bs[bu][bBase + ni * 1024 + c1];
    }
    SA(bu2, kc);
    PHTOP();
#pragma unroll
    for (int mi = 0; mi < 4; ++mi)
#pragma unroll
      for (int ni = 0; ni < 2; ++ni)
#pragma unroll
        for (int kk = 0; kk < 2; ++kk)
          acc[mi][ni] = __builtin_amdgcn_mfma_f32_16x16x32_bf16(a[mi][kk], b[ni][kk], acc[mi][ni], 0, 0, 0);
    PHEND();

    // ---- ph1: a(all) x b23; stage B(U+2); counted vmcnt(6) ----
#pragma unroll
    for (int ni = 0; ni < 2; ++ni) {
      b[ni][0] = *(const bf16x8*)&Bs[bu][bBase + (ni + 2) * 1024 + c0];
      b[ni][1] = *(const bf16x8*)&Bs[bu][bBase + (ni + 2) * 1024 + c1];
    }
    SB(bu2, kc);
    PHTOP();
#pragma unroll
    for (int mi = 0; mi < 4; ++mi)
#pragma unroll
      for (int ni = 0; ni < 2; ++ni)
#pragma unroll
        for (int kk = 0; kk < 2; ++kk)
          acc[mi][ni + 2] = __builtin_amdgcn_mfma_f32_16x16x32_bf16(a[mi][kk], b[ni][kk], acc[mi][ni + 2], 0, 0, 0);
    PHENDW();

    bu = (bu == 2) ? 0 : bu + 1;
    bu2 = (bu2 == 2) ? 0 : bu2 + 1;
  }
#undef SA
#undef SB
#undef PHTOP
#undef PHEND
#undef PHENDW

  const int row0 = bm * 128 + wm * 64;
  const int col0 = bn * 256 + wn * 64;
#pragma unroll
  for (int mi = 0; mi < 4; ++mi)
#pragma unroll
    for (int ni = 0; ni < 4; ++ni)
#pragma unroll
      for (int r = 0; r < 4; ++r)
        C[(size_t)(row0 + mi * 16 + lg * 4 + r) * N + (col0 + ni * 16 + lr)] =
            (__bf16)acc[mi][ni][r];
}

// ---------------- GEMM2: r13 8-phase 256x256 kernel (unchanged, tail-free) -
template <typename OutT>
__global__ __launch_bounds__(512) void k_gemm8p(const __bf16* __restrict__ A,
                                                const __bf16* __restrict__ B,
                                                OutT* __restrict__ C,
                                                int M, int N, int K) {
  __shared__ __align__(16) __bf16 As[2][2][128 * 64];  // 64 KiB
  __shared__ __align__(16) __bf16 Bs[2][2][128 * 64];  // 64 KiB
  const int t = threadIdx.x;
  const int l = t & 63;
  const int w = t >> 6;
  const int wm = w >> 2;
  const int wn = w & 3;
  const int lr = l & 15, lg = l >> 4;
  const int sw = lr & 7;
  const int bm = blockIdx.y, bn = blockIdx.x;

  const int srow = t >> 3;
  const int scol = ((t & 7) ^ (srow & 7)) << 3;
  const __bf16* pa0 = A + (size_t)(bm * 256 +   0 + srow) * K + scol;
  const __bf16* pa1 = A + (size_t)(bm * 256 +  64 + srow) * K + scol;
  const __bf16* pa2 = A + (size_t)(bm * 256 + 128 + srow) * K + scol;
  const __bf16* pa3 = A + (size_t)(bm * 256 + 192 + srow) * K + scol;
  const __bf16* pb0 = B + (size_t)(bn * 256 +   0 + srow) * K + scol;
  const __bf16* pb1 = B + (size_t)(bn * 256 +  64 + srow) * K + scol;
  const __bf16* pb2 = B + (size_t)(bn * 256 + 128 + srow) * K + scol;
  const __bf16* pb3 = B + (size_t)(bn * 256 + 192 + srow) * K + scol;
  const int ldst = t * 8;

#define SA0(buf, kc) { gld_lds16(pa0 + (kc), &As[buf][0][ldst]); gld_lds16(pa1 + (kc), &As[buf][0][4096 + ldst]); }
#define SA1(buf, kc) { gld_lds16(pa2 + (kc), &As[buf][1][ldst]); gld_lds16(pa3 + (kc), &As[buf][1][4096 + ldst]); }
#define SB0(buf, kc) { gld_lds16(pb0 + (kc), &Bs[buf][0][ldst]); gld_lds16(pb1 + (kc), &Bs[buf][0][4096 + ldst]); }
#define SB1(buf, kc) { gld_lds16(pb2 + (kc), &Bs[buf][1][ldst]); gld_lds16(pb3 + (kc), &Bs[buf][1][4096 + ldst]); }

  const int c0 = ((lg ^ sw) * 8);
  const int c1 = (((lg ^ sw) ^ 4) * 8);
  const int aRow = lr;
  const int bRow = (wn & 1) * 64 + lr;

#define RDA(mi0, cur)                                                          \
  _Pragma("unroll") for (int mi = 0; mi < 4; ++mi) {                           \
    a[mi][0] = *(const bf16x8*)&As[cur][wm][(((mi0) + mi) * 16 + aRow) * 64 + c0]; \
    a[mi][1] = *(const bf16x8*)&As[cur][wm][(((mi0) + mi) * 16 + aRow) * 64 + c1]; \
  }
#define RDB(bv, ni0, cur)                                                      \
  _Pragma("unroll") for (int ni = 0; ni < 2; ++ni) {                           \
    bv[ni][0] = *(const bf16x8*)&Bs[cur][wn >> 1][(((ni0) + ni) * 16 + bRow) * 64 + c0]; \
    bv[ni][1] = *(const bf16x8*)&Bs[cur][wn >> 1][(((ni0) + ni) * 16 + bRow) * 64 + c1]; \
  }
#define PHTOP()                                        \
  asm volatile("" ::: "memory");                       \
  __builtin_amdgcn_s_barrier();                        \
  asm volatile("s_waitcnt lgkmcnt(0)" ::: "memory");   \
  __builtin_amdgcn_s_setprio(1)
#define PHEND()                                        \
  __builtin_amdgcn_s_setprio(0);                       \
  asm volatile("" ::: "memory");                       \
  __builtin_amdgcn_s_barrier()
#define PHENDW()                                       \
  __builtin_amdgcn_s_setprio(0);                       \
  asm volatile("s_waitcnt vmcnt(8)" ::: "memory");     \
  __builtin_amdgcn_s_barrier()
#define MMA16(am0, bv, ni0)                                                    \
  _Pragma("unroll") for (int mi = 0; mi < 4; ++mi)                             \
  _Pragma("unroll") for (int ni = 0; ni < 2; ++ni)                             \
  _Pragma("unroll") for (int kk = 0; kk < 2; ++kk)                             \
    acc[(am0) + mi][(ni0) + ni] = __builtin_amdgcn_mfma_f32_16x16x32_bf16(     \
        a[mi][kk], bv[ni][kk], acc[(am0) + mi][(ni0) + ni], 0, 0, 0);

  f32x4 acc[8][4] = {};
  const int nt = K >> 6;
  const int niter = nt >> 1;

  {
    const int k1 = (nt > 1 ? 1 : 0) << 6;
    SB0(0, 0); SB1(0, 0); SA0(0, 0); SA1(0, 0);
    SB0(1, k1); SB1(1, k1); SA0(1, k1); SA1(1, k1);
  }
  asm volatile("s_waitcnt vmcnt(8)" ::: "memory");
  asm volatile("" ::: "memory");
  __builtin_amdgcn_s_barrier();
  asm volatile("" ::: "memory");

  for (int i = 0; i < niter; ++i) {
    const int k2 = (2 * i + 2 < nt ? 2 * i + 2 : nt - 1) << 6;
    const int k3 = (2 * i + 3 < nt ? 2 * i + 3 : nt - 1) << 6;
    bf16x8 a[4][2], b0[2][2], b1[2][2];

    RDA(0, 0); RDB(b0, 0, 0);
    PHTOP(); MMA16(0, b0, 0); PHEND();
    RDB(b1, 2, 0);
    PHTOP(); MMA16(0, b1, 2); PHEND();
    RDA(4, 0);
    SB0(0, k2); SB1(0, k2);
    PHTOP(); MMA16(4, b1, 2); PHEND();
    SA0(0, k2); SA1(0, k2);
    PHTOP(); MMA16(4, b0, 0); PHENDW();

    RDA(0, 1); RDB(b0, 0, 1);
    PHTOP(); MMA16(0, b0, 0); PHEND();
    RDB(b1, 2, 1);
    PHTOP(); MMA16(0, b1, 2); PHEND();
    RDA(4, 1);
    SB0(1, k3); SB1(1, k3);
    PHTOP(); MMA16(4, b1, 2); PHEND();
    SA0(1, k3); SA1(1, k3);
    PHTOP(); MMA16(4, b0, 0); PHENDW();
  }
#undef SA0
#undef SA1
#undef SB0
#undef SB1
#undef RDA
#undef RDB
#undef PHTOP
#undef PHEND
#undef PHENDW
#undef MMA16

  const int row0 = bm * 256 + wm * 128;
  const int col0 = bn * 256 + wn * 64;
#pragma unroll
  for (int mi = 0; mi < 8; ++mi)
#pragma unroll
    for (int ni = 0; ni < 4; ++ni)
#pragma unroll
      for (int r = 0; r < 4; ++r)
        C[(size_t)(row0 + mi * 16 + lg * 4 + r) * N + (col0 + ni * 16 + lr)] =
            (OutT)acc[mi][ni][r];
}

// ---------------- fused RoPE + RMSNorm (in-place on Q and K regions) -------
__global__ __launch_bounds__(256) void k_rope_norm(__bf16* __restrict__ qkv,
                                                   const float* __restrict__ cosT,
                                                   const float* __restrict__ sinT) {
  const int task = blockIdx.x * 4 + (threadIdx.x >> 6);
  const int l = threadIdx.x & 63;
  const int m = task / 40;          // row in [0, 4096)
  const int h = task - m * 40;      // 0..31 = Q heads, 32..39 = K heads
  const int s = m & (SEQ - 1);
  const bool isQ = h < 32;
  const int col = isQ ? h * 128 : 4096 + (h - 32) * 128;
  __bf16* p = qkv + (size_t)m * QKVN + col + l * 2;
  float e = (float)p[0], o = (float)p[1];
  float c = cosT[s * 64 + l], sn = sinT[s * 64 + l];
  float e2 = e * c - o * sn;
  float o2 = e * sn + o * c;
  float ss = e2 * e2 + o2 * o2;
#pragma unroll
  for (int off = 32; off > 0; off >>= 1) ss += __shfl_xor(ss, off);
  float r = rsqrtf(ss * (1.0f / 128.0f) + 1e-5f);
  if (isQ) r *= 0.08838834764831845f;  // fold 1/sqrt(HEAD_DIM) into Q
  p[0] = (__bf16)(e2 * r);
  p[1] = (__bf16)(o2 * r);
}

// ---------------- V transpose: qkv V region (b,s,g,d) -> vt (b,g,d,s) ------
__global__ __launch_bounds__(256) void k_transpose_v(const __bf16* __restrict__ qkv,
                                                     __bf16* __restrict__ vt) {
  __shared__ __bf16 tile[64][136];  // padded row, no bank conflicts
  const int t = threadIdx.x;
  const int st = blockIdx.x, bg = blockIdx.y;
  const int b = bg >> 3, g = bg & 7;
  const int s0 = st * 64;
#pragma unroll
  for (int p = 0; p < 4; ++p) {
    int row = p * 16 + (t >> 4);
    int co = (t & 15) * 8;
    *(bf16x8*)&tile[row][co] =
        *(const bf16x8*)&qkv[(size_t)(b * SEQ + s0 + row) * QKVN + 5120 + g * 128 + co];
  }
  __syncthreads();
#pragma unroll
  for (int p = 0; p < 4; ++p) {
    int d = p * 32 + (t >> 3);
    int so = (t & 7) * 8;
    bf16x8 v;
#pragma unroll
    for (int j = 0; j < 8; ++j) v[j] = tile[so + j][d];
    *(bf16x8*)&vt[((size_t)bg * 128 + d) * SEQ + s0 + so] = v;
  }
}

// ---------------- causal flash attention (GQA) — r9/r13 version ------------
__global__ __launch_bounds__(256) void k_flash(const __bf16* __restrict__ qkv,
                                               const __bf16* __restrict__ vt,
                                               __bf16* __restrict__ attno) {
  __shared__ __bf16 Ks[64 * 128];   // [kv][d], swizzled
  __shared__ __bf16 Vs[128 * 64];   // [d][kv], swizzled
  __shared__ __bf16 Ps[4][16 * 64]; // per-wave [q][kv], swizzled
  const int t = threadIdx.x, w = t >> 6, l = t & 63;
  const int lr = l & 15, lg = l >> 4;
  const int bh = blockIdx.y;        // b*32 + h
  const int b = bh >> 5, h = bh & 31, g = h >> 2;
  const int qt0 = blockIdx.x, qt1 = 31 - (int)blockIdx.x;

  const __bf16* kp = qkv + 4096 + (size_t)(b * SEQ + (t >> 4)) * QKVN + g * 128 +
                     (((t & 15) ^ ((t >> 4) & 7)) * 8);
  const __bf16* vp = vt + (size_t)(b * 8 + g) * 128 * SEQ + (size_t)(t >> 3) * SEQ +
                     (((t & 7) ^ ((t >> 3) & 7)) * 8);
  const int wbase = (t & ~63) * 8;
  const int sw = lr & 7;

  for (int pass = 0; pass < 2; ++pass) {
    const int qt = (pass == 0) ? qt0 : qt1;

    const __bf16* Qb = qkv + (size_t)(b * SEQ + qt * 64 + w * 16 + lr) * QKVN + h * 128;
    bf16x8 qf[4];
#pragma unroll
    for (int kk = 0; kk < 4; ++kk) qf[kk] = *(const bf16x8*)&Qb[kk * 32 + lg * 8];

    f32x4 oacc[8] = {};
    float mrow[4], lsum[4];
#pragma unroll
    for (int r = 0; r < 4; ++r) { mrow[r] = -1e30f; lsum[r] = 0.f; }

    for (int kt = 0; kt <= qt; ++kt) {
      const size_t kv0 = (size_t)kt * 64;
#pragma unroll
      for (int i = 0; i < 4; ++i)
        gld_lds16(kp + (kv0 + i * 16) * QKVN, &Ks[i * 2048 + wbase]);
#pragma unroll
      for (int i = 0; i < 4; ++i)
        gld_lds16(vp + (size_t)i * 32 * SEQ + kv0, &Vs[i * 2048 + wbase]);
      __syncthreads();

      // S = Q K^T
      f32x4 sc[4] = {};
      __builtin_amdgcn_s_setprio(1);
#pragma unroll
      for (int kk = 0; kk < 4; ++kk)
#pragma unroll
        for (int n = 0; n < 4; ++n) {
          bf16x8 kf = *(const bf16x8*)&Ks[(n * 16 + lr) * 128 + ((kk * 4 + lg) ^ sw) * 8];
          sc[n] = __builtin_amdgcn_mfma_f32_16x16x32_bf16(qf[kk], kf, sc[n], 0, 0, 0);
        }
      __builtin_amdgcn_s_setprio(0);

      if (kt == qt) {  // diagonal tile: causal mask
#pragma unroll
        for (int n = 0; n < 4; ++n)
#pragma unroll
          for (int r = 0; r < 4; ++r)
            if (n * 16 + lr > w * 16 + lg * 4 + r) sc[n][r] = -1e30f;
      }

      // online softmax with defer-max (T13, THR=8)
      float pml[4];
      float need = -1e30f;
#pragma unroll
      for (int r = 0; r < 4; ++r) {
        pml[r] = fmaxf(fmaxf(sc[0][r], sc[1][r]), fmaxf(sc[2][r], sc[3][r]));
        need = fmaxf(need, pml[r] - mrow[r]);
      }
      if (__all(need <= 8.0f)) {
#pragma unroll
        for (int r = 0; r < 4; ++r) {
          float ps = 0.f;
#pragma unroll
          for (int n = 0; n < 4; ++n) { sc[n][r] = __expf(sc[n][r] - mrow[r]); ps += sc[n][r]; }
#pragma unroll
          for (int off = 8; off > 0; off >>= 1) ps += __shfl_xor(ps, off);
          lsum[r] += ps;
        }
      } else {
#pragma unroll
        for (int r = 0; r < 4; ++r) {
          float pm = pml[r];
#pragma unroll
          for (int off = 8; off > 0; off >>= 1) pm = fmaxf(pm, __shfl_xor(pm, off));
          float mn = fmaxf(mrow[r], pm);
          float corr = __expf(mrow[r] - mn);
          mrow[r] = mn;
          float ps = 0.f;
#pragma unroll
          for (int n = 0; n < 4; ++n) { sc[n][r] = __expf(sc[n][r] - mn); ps += sc[n][r]; }
#pragma unroll
          for (int off = 8; off > 0; off >>= 1) ps += __shfl_xor(ps, off);
          lsum[r] = lsum[r] * corr + ps;
#pragma unroll
          for (int dn = 0; dn < 8; ++dn) oacc[dn][r] *= corr;
        }
      }

      // P -> LDS (swizzled)
#pragma unroll
      for (int n = 0; n < 4; ++n)
#pragma unroll
        for (int r = 0; r < 4; ++r) {
          int row = lg * 4 + r;
          Ps[w][row * 64 + (((n * 2 + (lr >> 3)) ^ (row & 7)) * 8) + (lr & 7)] = (__bf16)sc[n][r];
        }

      // O += P V
      __builtin_amdgcn_s_setprio(1);
#pragma unroll
      for (int ks = 0; ks < 2; ++ks) {
        bf16x8 pf = *(const bf16x8*)&Ps[w][lr * 64 + ((ks * 4 + lg) ^ sw) * 8];
#pragma unroll
        for (int dn = 0; dn < 8; ++dn) {
          bf16x8 vf = *(const bf16x8*)&Vs[(dn * 16 + lr) * 64 + ((ks * 4 + lg) ^ sw) * 8];
          oacc[dn] = __builtin_amdgcn_mfma_f32_16x16x32_bf16(pf, vf, oacc[dn], 0, 0, 0);
        }
      }
      __builtin_amdgcn_s_setprio(0);
      __syncthreads();
    }

    float inv[4];
#pragma unroll
    for (int r = 0; r < 4; ++r) inv[r] = __builtin_amdgcn_rcpf(lsum[r]);
    __bf16* Ob = attno + (size_t)(b * SEQ + qt * 64 + w * 16) * DIMSZ + h * 128;
#pragma unroll
    for (int dn = 0; dn < 8; ++dn)
#pragma unroll
      for (int r = 0; r < 4; ++r)
        Ob[(size_t)(lg * 4 + r) * DIMSZ + dn * 16 + lr] = (__bf16)(oacc[dn][r] * inv[r]);
  }
}

// ---------------- host launcher --------------------------------------------
extern "C" void kernel_launch(void* const* d_in, const int* in_sizes, int n_in,
                              void* d_out, int out_size, void* d_ws, size_t ws_size,
                              hipStream_t stream) {
  const float* x    = (const float*)d_in[0];
  const float* wq   = (const float*)d_in[1];
  const float* wk   = (const float*)d_in[2];
  const float* wv   = (const float*)d_in[3];
  const float* wo   = (const float*)d_in[4];
  const float* cosT = (const float*)d_in[5];
  const float* sinT = (const float*)d_in[6];
  // d_in[7] (mask) implemented as causal; d_in[8] (start_pos) == 0.

  char* ws = (char*)d_ws;
  __bf16* xb    = (__bf16*)(ws);                    // 4096x4096        (32 MiB)
  __bf16* wqkvb = (__bf16*)(ws + 33554432);         // 6144x4096        (48 MiB)
  __bf16* qkvb  = (__bf16*)(ws + 83886080);         // 4096x6144        (48 MiB)
  __bf16* wob   = (__bf16*)(ws + 134217728);        // 4096x4096        (32 MiB)
  __bf16* vt    = (__bf16*)(ws + 167772160);        // 16x128x2048      ( 8 MiB)
  __bf16* attno = (__bf16*)(ws + 176160768);        // 4096x4096        (32 MiB)
  float* out = (float*)d_out;

  // fp32 -> bf16 conversions, single merged launch
  k_cvt5<<<4096, 256, 0, stream>>>(x, wq, wk, wv, wo, xb, wqkvb, wob);

  // QKV projection: 128x256 tiles -> grid (24, 32) = 768 blocks = 3 exact
  // rounds (zero tail; r13 PM: packing was the remaining GEMM1 loss)
  k_gemm128x256<<<dim3(24, 32), 512, 0, stream>>>(xb, wqkvb, qkvb, 4096, QKVN, 4096);
  // RoPE + RMSNorm on Q,K (in place), attention scale folded into Q
  k_rope_norm<<<40960, 256, 0, stream>>>(qkvb, cosT, sinT);
  // V -> V^T for contiguous PV operand reads
  k_transpose_v<<<dim3(32, 16), 256, 0, stream>>>(qkvb, vt);
  // causal GQA flash attention (paired q-tiles, single-buffer KV)
  k_flash<<<dim3(16, 64), 256, 0, stream>>>(qkvb, vt, attno);
  // output projection: 256x256 -> grid (16, 16) = 256 blocks = 1 exact round
  k_gemm8p<float><<<dim3(16, 16), 512, 0, stream>>>(attno, wob, out, 4096, DIMSZ, 4096);
}